// Round 1
// baseline (2629.213 us; speedup 1.0000x reference)
//
#include <hip/hip_runtime.h>
#include <math.h>

// ---------------------------------------------------------------------------
// CoTracker correlation-embedding pipeline, fp32 baseline.
// Dims: B=1, S=8, N=1024, C=128, G=7, GG=49, K1=2401, H1=384, H2=256, D=1110
// Input order (setup_inputs dict order — INTERLEAVED!):
//   0:fmaps0 1:track0 2:fmaps1 3:track1 4:fmaps2 5:track2 6:fmaps3 7:track3
//   8:coords 9:vis 10:conf 11:w1 12:b1 13:w2 14:b2 15:time_emb
// Output: (1, N, S, 1110) float32, row = n*8+s.
// ---------------------------------------------------------------------------

#define SN 8
#define NN 1024
#define CC 128
#define GG 49
#define K1 2401
#define H1 384
#define H2 256
#define DOUT 1110

// Kernel A: per-n block; loop s. Build 8x8xC patch (LDS), bilinear -> samp
// (49xC LDS), then vol[row][ab*49+ij] = sum_c samp[ab][c]*trk[ij][c].
// LDS: r1 = union(patch[128][67], trk[49 rows stride 132]); samp[49 stride 132].
__global__ __launch_bounds__(256) void sample_vol_kernel(
    const float* __restrict__ fmap,   // (S, C, H, W)
    const float* __restrict__ track,  // (GG, N, C)
    const float* __restrict__ coords, // (S, N, 2)
    float* __restrict__ vol,          // (s_count*N, 2401)
    int H, int W, int lvl, int s_begin, int s_count)
{
    __shared__ __align__(16) float r1[8576];       // patch(8576) / trk(6468)
    __shared__ __align__(16) float samp[49 * 132]; // 6468
    const int n = blockIdx.x;
    const int t = threadIdx.x;
    const float inv = 1.0f / (float)(1 << lvl);

    for (int sl = 0; sl < s_count; ++sl) {
        const int s = s_begin + sl;
        const float cx = coords[((size_t)s * NN + n) * 2 + 0] * inv;
        const float cy = coords[((size_t)s * NN + n) * 2 + 1] * inv;
        const float fxf = floorf(cx), fyf = floorf(cy);
        const float wx = cx - fxf, wy = cy - fyf;
        const int fx = (int)fxf, fy = (int)fyf;
        const float w00 = (1.f - wx) * (1.f - wy);
        const float w10 = wx * (1.f - wy);
        const float w01 = (1.f - wx) * wy;
        const float w11 = wx * wy;

        __syncthreads();  // previous iter readers of r1/samp done
        // ---- load 8x8 patch per channel (clamped), mostly coalesced ----
        for (int idx = t; idx < CC * 64; idx += 256) {
            int u = idx & 7, v = (idx >> 3) & 7, c = idx >> 6;
            int x = min(max(fx + u - 3, 0), W - 1);
            int y = min(max(fy + v - 3, 0), H - 1);
            r1[c * 67 + v * 8 + u] =
                fmap[(((size_t)s * CC + c) * H + y) * W + x];
        }
        __syncthreads();
        // ---- bilinear: samp[ab][c] ----
        for (int idx = t; idx < GG * CC; idx += 256) {
            int p = idx >> 7, c = idx & 127;
            int a = p / 7, b = p % 7;  // a = x-offset idx, b = y-offset idx
            const float* P = &r1[c * 67];
            samp[p * 132 + c] = w00 * P[b * 8 + a] + w10 * P[b * 8 + a + 1] +
                                w01 * P[(b + 1) * 8 + a] + w11 * P[(b + 1) * 8 + a + 1];
        }
        __syncthreads();
        // ---- load track[n] into r1 (stride 132) ----
        for (int idx = t; idx < GG * CC; idx += 256) {
            int ij = idx >> 7, c = idx & 127;
            r1[ij * 132 + c] = track[((size_t)ij * NN + n) * CC + c];
        }
        __syncthreads();
        // ---- vol: 2401 outputs, 7x2 register tile, float4 LDS reads ----
        {
            const int ta = t >> 5;   // 0..7  (ab = ta + 8k)
            const int tj = t & 31;   // ij = tj (+32)
            const int nk = (48 - ta) / 8 + 1;      // 7 for ta==0 else 6
            const int nm = (tj <= 16) ? 2 : 1;
            float acc[7][2];
            #pragma unroll
            for (int k = 0; k < 7; ++k) { acc[k][0] = 0.f; acc[k][1] = 0.f; }
            for (int c4 = 0; c4 < CC / 4; ++c4) {
                float4 tb0 = *(const float4*)&r1[tj * 132 + c4 * 4];
                float4 tb1 = tb0;
                if (nm == 2) tb1 = *(const float4*)&r1[(tj + 32) * 132 + c4 * 4];
                #pragma unroll
                for (int k = 0; k < 7; ++k) {
                    if (k < nk) {
                        float4 sa = *(const float4*)&samp[(ta + 8 * k) * 132 + c4 * 4];
                        acc[k][0] += sa.x * tb0.x + sa.y * tb0.y + sa.z * tb0.z + sa.w * tb0.w;
                        if (nm == 2)
                            acc[k][1] += sa.x * tb1.x + sa.y * tb1.y + sa.z * tb1.z + sa.w * tb1.w;
                    }
                }
            }
            float* vrow = vol + ((size_t)sl * NN + n) * K1;
            #pragma unroll
            for (int k = 0; k < 7; ++k) {
                if (k < nk) {
                    int ab = ta + 8 * k;
                    vrow[ab * GG + tj] = acc[k][0];
                    if (nm == 2) vrow[ab * GG + tj + 32] = acc[k][1];
                }
            }
        }
    }
}

// Kernel B: H = gelu(vol @ w1 + b1).  M x 2401 @ 2401 x 384.
__global__ __launch_bounds__(256) void gemm_gelu_kernel(
    const float* __restrict__ A,    // M x K1
    const float* __restrict__ Bw,   // K1 x 384
    const float* __restrict__ bias, // 384
    float* __restrict__ Hout)       // M x 384
{
    __shared__ float As[64][17];
    __shared__ __align__(16) float Bs[16][68];
    const int m0 = blockIdx.x * 64;
    const int n0 = blockIdx.y * 64;
    const int t = threadIdx.x;
    const int tx = t & 15, ty = t >> 4;
    float acc[4][4] = {};
    for (int k0 = 0; k0 < K1; k0 += 16) {
        #pragma unroll
        for (int i = 0; i < 4; ++i) {
            int idx = t + i * 256;
            int kk = idx & 15, row = idx >> 4;
            int k = k0 + kk;
            As[row][kk] = (k < K1) ? A[(size_t)(m0 + row) * K1 + k] : 0.f;
        }
        {
            int col4 = t & 15, kr = t >> 4;
            int k = k0 + kr;
            float4 bv = make_float4(0.f, 0.f, 0.f, 0.f);
            if (k < K1) bv = *(const float4*)&Bw[(size_t)k * H1 + n0 + col4 * 4];
            *(float4*)&Bs[kr][col4 * 4] = bv;
        }
        __syncthreads();
        #pragma unroll
        for (int kk = 0; kk < 16; ++kk) {
            float a[4];
            #pragma unroll
            for (int i = 0; i < 4; ++i) a[i] = As[ty * 4 + i][kk];
            float4 bv = *(const float4*)&Bs[kk][tx * 4];
            const float b[4] = {bv.x, bv.y, bv.z, bv.w};
            #pragma unroll
            for (int i = 0; i < 4; ++i)
                #pragma unroll
                for (int j = 0; j < 4; ++j) acc[i][j] += a[i] * b[j];
        }
        __syncthreads();
    }
    #pragma unroll
    for (int i = 0; i < 4; ++i) {
        int row = m0 + ty * 4 + i;
        float4 o;
        #pragma unroll
        for (int j = 0; j < 4; ++j) {
            float x = acc[i][j] + bias[n0 + tx * 4 + j];
            ((float*)&o)[j] = 0.5f * x * (1.f + erff(x * 0.70710678118654752f));
        }
        *(float4*)&Hout[(size_t)row * H1 + n0 + tx * 4] = o;
    }
}

// Kernel C: out slice = H @ w2 + b2 + time_emb.  M x 384 @ 384 x 256.
__global__ __launch_bounds__(256) void gemm_out_kernel(
    const float* __restrict__ A,    // M x 384
    const float* __restrict__ Bw,   // 384 x 256
    const float* __restrict__ bias, // 256
    const float* __restrict__ te,   // (8, 1110)
    float* __restrict__ out,        // (N, 8, 1110)
    int s_begin, int lvl)
{
    __shared__ __align__(16) float As[64][20];
    __shared__ __align__(16) float Bs[16][68];
    const int m0 = blockIdx.x * 64;
    const int n0 = blockIdx.y * 64;
    const int t = threadIdx.x;
    const int tx = t & 15, ty = t >> 4;
    float acc[4][4] = {};
    for (int k0 = 0; k0 < H1; k0 += 16) {
        {
            int kk4 = t & 3, row = t >> 2;
            *(float4*)&As[row][kk4 * 4] =
                *(const float4*)&A[(size_t)(m0 + row) * H1 + k0 + kk4 * 4];
            int col4 = t & 15, kr = t >> 4;
            *(float4*)&Bs[kr][col4 * 4] =
                *(const float4*)&Bw[(size_t)(k0 + kr) * H2 + n0 + col4 * 4];
        }
        __syncthreads();
        #pragma unroll
        for (int kk = 0; kk < 16; ++kk) {
            float a[4];
            #pragma unroll
            for (int i = 0; i < 4; ++i) a[i] = As[ty * 4 + i][kk];
            float4 bv = *(const float4*)&Bs[kk][tx * 4];
            const float b[4] = {bv.x, bv.y, bv.z, bv.w};
            #pragma unroll
            for (int i = 0; i < 4; ++i)
                #pragma unroll
                for (int j = 0; j < 4; ++j) acc[i][j] += a[i] * b[j];
        }
        __syncthreads();
    }
    #pragma unroll
    for (int i = 0; i < 4; ++i) {
        int row = m0 + ty * 4 + i;
        int sl = row >> 10, n = row & 1023;
        int s = s_begin + sl;
        size_t ob = ((size_t)n * SN + s) * DOUT;
        #pragma unroll
        for (int j = 0; j < 4; ++j) {
            int col = n0 + tx * 4 + j;
            int dcol = 2 + lvl * H2 + col;
            out[ob + dcol] = acc[i][j] + bias[col] + te[s * DOUT + dcol];
        }
    }
}

// Kernel D: vis, conf, rel_emb(84) + time_emb. One block per (n,s) row.
__global__ __launch_bounds__(128) void tail_kernel(
    const float* __restrict__ coords, const float* __restrict__ vis,
    const float* __restrict__ conf, const float* __restrict__ te,
    float* __restrict__ out)
{
    const int b = blockIdx.x;           // row = n*8+s = b
    const int n = b >> 3, s = b & 7;
    const int d = threadIdx.x;
    if (d >= 86) return;
    const size_t ob = (size_t)b * DOUT;
    if (d == 0) {
        out[ob + 0] = vis[(size_t)s * NN + n] + te[s * DOUT + 0];
    } else if (d == 1) {
        out[ob + 1] = conf[(size_t)s * NN + n] + te[s * DOUT + 1];
    } else {
        int rd = d - 2;  // 0..83
        float cx = coords[((size_t)s * NN + n) * 2 + 0];
        float cy = coords[((size_t)s * NN + n) * 2 + 1];
        float rfx = 0.f, rfy = 0.f, rbx = 0.f, rby = 0.f;
        if (s < SN - 1) {
            rfx = cx - coords[((size_t)(s + 1) * NN + n) * 2 + 0];
            rfy = cy - coords[((size_t)(s + 1) * NN + n) * 2 + 1];
        }
        if (s > 0) {
            rbx = cx - coords[((size_t)(s - 1) * NN + n) * 2 + 0];
            rby = cy - coords[((size_t)(s - 1) * NN + n) * 2 + 1];
        }
        float r4[4] = {rfx / 128.f, rfy / 96.f, rbx / 128.f, rby / 96.f};
        float val;
        if (rd < 4) {
            val = r4[rd];
        } else if (rd < 44) {
            int q = rd - 4; int deg = q >> 2, comp = q & 3;
            val = sinf(r4[comp] * (float)(1 << deg));
        } else {
            int q = rd - 44; int deg = q >> 2, comp = q & 3;
            val = sinf(r4[comp] * (float)(1 << deg) + 1.57079632679489662f);
        }
        int od = 1026 + rd;
        out[ob + od] = val + te[s * DOUT + od];
    }
}

extern "C" void kernel_launch(void* const* d_in, const int* in_sizes, int n_in,
                              void* d_out, int out_size, void* d_ws, size_t ws_size,
                              hipStream_t stream) {
    const float* fmaps[4] = {(const float*)d_in[0], (const float*)d_in[2],
                             (const float*)d_in[4], (const float*)d_in[6]};
    const float* track[4] = {(const float*)d_in[1], (const float*)d_in[3],
                             (const float*)d_in[5], (const float*)d_in[7]};
    const float* coords = (const float*)d_in[8];
    const float* vis    = (const float*)d_in[9];
    const float* conf   = (const float*)d_in[10];
    const float* w1     = (const float*)d_in[11];
    const float* b1     = (const float*)d_in[12];
    const float* w2     = (const float*)d_in[13];
    const float* b2     = (const float*)d_in[14];
    const float* te     = (const float*)d_in[15];
    float* out = (float*)d_out;

    const int Hs[4] = {96, 48, 24, 12};
    const int Ws[4] = {128, 64, 32, 16};

    // Workspace: vol (rows x 2401) + h (rows x 384). Chunk by s if ws is small.
    const size_t need_full = ((size_t)SN * NN * K1 + (size_t)SN * NN * H1) * 4;
    const int s_chunk = (ws_size >= need_full) ? SN : 1;

    for (int lvl = 0; lvl < 4; ++lvl) {
        for (int s0 = 0; s0 < SN; s0 += s_chunk) {
            const int rows = s_chunk * NN;
            float* vol  = (float*)d_ws;
            float* hbuf = vol + (size_t)rows * K1;
            sample_vol_kernel<<<NN, 256, 0, stream>>>(
                fmaps[lvl], track[lvl], coords, vol, Hs[lvl], Ws[lvl], lvl, s0, s_chunk);
            gemm_gelu_kernel<<<dim3(rows / 64, H1 / 64), 256, 0, stream>>>(
                vol, w1, b1, hbuf);
            gemm_out_kernel<<<dim3(rows / 64, H2 / 64), 256, 0, stream>>>(
                hbuf, w2, b2, te, out, s0, lvl);
        }
    }
    tail_kernel<<<SN * NN, 128, 0, stream>>>(coords, vis, conf, te, out);
}

// Round 2
// 695.796 us; speedup vs baseline: 3.7787x; 3.7787x over previous
//
#include <hip/hip_runtime.h>
#include <math.h>

// ---------------------------------------------------------------------------
// CoTracker correlation-embedding pipeline, bf16 MFMA version.
// B=1, S=8, N=1024, C=128, G=7, GG=49, K1=2401 (pad 2432), H1=384, H2=256.
// Input order: 0:fmaps0 1:track0 2:fmaps1 3:track1 4:fmaps2 5:track2
//              6:fmaps3 7:track3 8:coords 9:vis 10:conf 11:w1 12:b1 13:w2
//              14:b2 15:time_emb.  Output: (1,N,8,1110) f32.
// ---------------------------------------------------------------------------

#define SN 8
#define NN 1024
#define CC 128
#define K1P 2432
#define H1 384
#define H2 256
#define DOUT 1110

typedef short bf16x8 __attribute__((ext_vector_type(8)));
typedef float f32x4 __attribute__((ext_vector_type(4)));

__device__ inline unsigned short f2b(float x) {  // RTNE f32 -> bf16
    union { float f; unsigned u; } v; v.f = x;
    unsigned r = v.u + 0x7FFFu + ((v.u >> 16) & 1u);
    return (unsigned short)(r >> 16);
}

__device__ inline void gll16(const void* g, void* l) {
    __builtin_amdgcn_global_load_lds(
        (const __attribute__((address_space(1))) void*)g,
        (__attribute__((address_space(3))) void*)l, 16, 0, 0);
}

// ---------------------------------------------------------------------------
// Kernel A: per-n block; track loaded ONCE; per s: patch -> bilinear(bf16) ->
// MFMA 49x49x128 -> vol row (bf16, padded to 2432 with zeros).
// ---------------------------------------------------------------------------
__global__ __launch_bounds__(256) void sample_vol_kernel(
    const float* __restrict__ fmap,   // (S, C, H, W)
    const float* __restrict__ track,  // (GG, N, C)
    const float* __restrict__ coords, // (S, N, 2)
    unsigned short* __restrict__ vol, // (s_count*N, 2432) bf16
    int H, int W, int lvl, int s_begin, int s_count)
{
    __shared__ float patch[CC * 67];                     // 34,304 B
    __shared__ __align__(16) unsigned short samp[64 * 136]; // 17,408 B
    __shared__ __align__(16) unsigned short trk[64 * 136];  // 17,408 B
    const int n = blockIdx.x, t = threadIdx.x;
    const int lane = t & 63, wv = t >> 6;
    const float inv = 1.0f / (float)(1 << lvl);

    // track[n] -> LDS bf16, once per block (row pad 136 => 2-way banks, free)
    for (int idx = t; idx < 49 * CC; idx += 256) {
        int ij = idx >> 7, c = idx & 127;
        trk[ij * 136 + c] = f2b(track[((size_t)ij * NN + n) * CC + c]);
    }

    const int pu = t & 7, pv = (t >> 3) & 7, pc0 = t >> 6;  // patch loader coords
    const int bc = t & 127, bp0 = t >> 7;                   // bilinear coords
    const int rsub = lane & 15, kq = lane >> 4;             // MFMA frag coords

    for (int sl = 0; sl < s_count; ++sl) {
        const int s = s_begin + sl;
        float cx = coords[((size_t)s * NN + n) * 2 + 0] * inv;
        float cy = coords[((size_t)s * NN + n) * 2 + 1] * inv;
        float fxf = floorf(cx), fyf = floorf(cy);
        float wx = cx - fxf, wy = cy - fyf;
        int fx = (int)fxf, fy = (int)fyf;
        float w00 = (1.f - wx) * (1.f - wy), w10 = wx * (1.f - wy);
        float w01 = (1.f - wx) * wy,         w11 = wx * wy;

        // ---- 8x8xC patch load (clamped); fixed (u,v) per thread ----
        {
            int x = min(max(fx + pu - 3, 0), W - 1);
            int y = min(max(fy + pv - 3, 0), H - 1);
            const float* gsrc = fmap + (size_t)s * CC * H * W + (size_t)y * W + x;
            const int pidx = pv * 8 + pu;
            #pragma unroll 8
            for (int i = 0; i < 32; ++i) {
                int c = pc0 + i * 4;
                patch[c * 67 + pidx] = gsrc[(size_t)c * H * W];
            }
        }
        __syncthreads();   // patch ready; also: all waves done with prev MFMA
        // ---- bilinear -> samp bf16 (fixed c per thread) ----
        {
            const float* P = &patch[bc * 67];
            for (int p = bp0; p < 49; p += 2) {
                int a = p / 7, b = p - a * 7;
                float v = w00 * P[b * 8 + a]       + w10 * P[b * 8 + a + 1]
                        + w01 * P[(b + 1) * 8 + a] + w11 * P[(b + 1) * 8 + a + 1];
                samp[p * 136 + bc] = f2b(v);
            }
        }
        __syncthreads();
        // ---- MFMA: wave wv owns row-tile mi=wv; vol[ab][ij]=sum_c samp*trk ----
        {
            f32x4 acc[4] = {};
            #pragma unroll
            for (int kk = 0; kk < 4; ++kk) {
                bf16x8 a = *(const bf16x8*)&samp[(wv * 16 + rsub) * 136 + kk * 32 + kq * 8];
                #pragma unroll
                for (int ni = 0; ni < 4; ++ni) {
                    bf16x8 b = *(const bf16x8*)&trk[(ni * 16 + rsub) * 136 + kk * 32 + kq * 8];
                    acc[ni] = __builtin_amdgcn_mfma_f32_16x16x32_bf16(a, b, acc[ni], 0, 0, 0);
                }
            }
            unsigned short* vrow = vol + ((size_t)sl * NN + n) * K1P;
            #pragma unroll
            for (int ni = 0; ni < 4; ++ni) {
                #pragma unroll
                for (int r = 0; r < 4; ++r) {
                    int ab = wv * 16 + kq * 4 + r;   // D: row=(l>>4)*4+reg
                    int ij = ni * 16 + rsub;         // D: col=l&15
                    if (ab < 49 && ij < 49) vrow[ab * 49 + ij] = f2b(acc[ni][r]);
                }
            }
            if (t < 31) vrow[2401 + t] = 0;  // zero K padding
        }
    }
}

// ---------------------------------------------------------------------------
// GEMM1: H = gelu(vol @ w1 + b1).  (rows x 2432) @ (2432 x 384), both bf16
// row-by-K; 128x128 tile, 4 waves (2x2), dbuf global_load_lds staging with
// both-sides XOR swizzle: phys_slot = r*4 + (seg ^ ((r>>1)&3)).
// ---------------------------------------------------------------------------
__global__ __launch_bounds__(256) void gemm1_kernel(
    const unsigned short* __restrict__ A,   // rows x 2432
    const unsigned short* __restrict__ Bt,  // 384 x 2432 (= w1^T)
    const float* __restrict__ bias,
    unsigned short* __restrict__ Hout)      // rows x 384
{
    __shared__ __align__(16) unsigned short As[2][128 * 32];
    __shared__ __align__(16) unsigned short Bs[2][128 * 32];
    const int m0 = blockIdx.x * 128, n0 = blockIdx.y * 128;
    const int t = threadIdx.x, lane = t & 63, wv = t >> 6;
    const int wm = wv >> 1, wn = wv & 1;
    const int rsub = lane & 15, kq = lane >> 4;

    const int dA0 = t, dA1 = t + 256;
    const int rA0 = dA0 >> 2, sA0 = (dA0 & 3) ^ ((rA0 >> 1) & 3);
    const int rA1 = dA1 >> 2, sA1 = (dA1 & 3) ^ ((rA1 >> 1) & 3);
    const unsigned short* gA0 = A  + (size_t)(m0 + rA0) * K1P + sA0 * 8;
    const unsigned short* gA1 = A  + (size_t)(m0 + rA1) * K1P + sA1 * 8;
    const unsigned short* gB0 = Bt + (size_t)(n0 + rA0) * K1P + sA0 * 8;
    const unsigned short* gB1 = Bt + (size_t)(n0 + rA1) * K1P + sA1 * 8;
    const int chunk0 = (t & ~63) * 8, chunk1 = (256 + (t & ~63)) * 8;

    f32x4 acc[4][4] = {};

    gll16(gA0, &As[0][chunk0]); gll16(gA1, &As[0][chunk1]);
    gll16(gB0, &Bs[0][chunk0]); gll16(gB1, &Bs[0][chunk1]);
    __syncthreads();

    const int NSTEP = K1P / 32;  // 76
    for (int st = 0; st < NSTEP; ++st) {
        int cur = st & 1;
        if (st + 1 < NSTEP) {
            size_t ko = (size_t)(st + 1) * 32;
            gll16(gA0 + ko, &As[cur ^ 1][chunk0]);
            gll16(gA1 + ko, &As[cur ^ 1][chunk1]);
            gll16(gB0 + ko, &Bs[cur ^ 1][chunk0]);
            gll16(gB1 + ko, &Bs[cur ^ 1][chunk1]);
        }
        bf16x8 af[4], bfr[4];
        #pragma unroll
        for (int mi = 0; mi < 4; ++mi) {
            int r = wm * 64 + mi * 16 + rsub;
            int phys = r * 4 + (kq ^ ((r >> 1) & 3));
            af[mi] = *(const bf16x8*)&As[cur][phys * 8];
        }
        #pragma unroll
        for (int ni = 0; ni < 4; ++ni) {
            int r = wn * 64 + ni * 16 + rsub;
            int phys = r * 4 + (kq ^ ((r >> 1) & 3));
            bfr[ni] = *(const bf16x8*)&Bs[cur][phys * 8];
        }
        #pragma unroll
        for (int mi = 0; mi < 4; ++mi)
            #pragma unroll
            for (int ni = 0; ni < 4; ++ni)
                acc[mi][ni] = __builtin_amdgcn_mfma_f32_16x16x32_bf16(
                    af[mi], bfr[ni], acc[mi][ni], 0, 0, 0);
        __syncthreads();  // drains vmcnt (next buf ready) + readers done
    }
    #pragma unroll
    for (int mi = 0; mi < 4; ++mi) {
        int row = m0 + wm * 64 + mi * 16 + kq * 4;
        #pragma unroll
        for (int ni = 0; ni < 4; ++ni) {
            int col = n0 + wn * 64 + ni * 16 + rsub;
            float bcol = bias[col];
            #pragma unroll
            for (int r = 0; r < 4; ++r) {
                float x = acc[mi][ni][r] + bcol;
                float g = 0.5f * x * (1.f + erff(x * 0.70710678118654752f));
                Hout[(size_t)(row + r) * H1 + col] = f2b(g);
            }
        }
    }
}

// ---------------------------------------------------------------------------
// GEMM2: out slice = H @ w2 + b2 + time_emb.  (rows x 384) @ (384 x 256).
// ---------------------------------------------------------------------------
__global__ __launch_bounds__(256) void gemm2_kernel(
    const unsigned short* __restrict__ A,   // rows x 384
    const unsigned short* __restrict__ Bt,  // 256 x 384 (= w2^T)
    const float* __restrict__ bias,
    const float* __restrict__ te,           // (8, 1110)
    float* __restrict__ out,                // (N, 8, 1110)
    int s_begin, int lvl)
{
    __shared__ __align__(16) unsigned short As[2][128 * 32];
    __shared__ __align__(16) unsigned short Bs[2][128 * 32];
    const int m0 = blockIdx.x * 128, n0 = blockIdx.y * 128;
    const int t = threadIdx.x, lane = t & 63, wv = t >> 6;
    const int wm = wv >> 1, wn = wv & 1;
    const int rsub = lane & 15, kq = lane >> 4;

    const int dA0 = t, dA1 = t + 256;
    const int rA0 = dA0 >> 2, sA0 = (dA0 & 3) ^ ((rA0 >> 1) & 3);
    const int rA1 = dA1 >> 2, sA1 = (dA1 & 3) ^ ((rA1 >> 1) & 3);
    const unsigned short* gA0 = A  + (size_t)(m0 + rA0) * H1 + sA0 * 8;
    const unsigned short* gA1 = A  + (size_t)(m0 + rA1) * H1 + sA1 * 8;
    const unsigned short* gB0 = Bt + (size_t)(n0 + rA0) * H1 + sA0 * 8;
    const unsigned short* gB1 = Bt + (size_t)(n0 + rA1) * H1 + sA1 * 8;
    const int chunk0 = (t & ~63) * 8, chunk1 = (256 + (t & ~63)) * 8;

    f32x4 acc[4][4] = {};

    gll16(gA0, &As[0][chunk0]); gll16(gA1, &As[0][chunk1]);
    gll16(gB0, &Bs[0][chunk0]); gll16(gB1, &Bs[0][chunk1]);
    __syncthreads();

    const int NSTEP = H1 / 32;  // 12
    for (int st = 0; st < NSTEP; ++st) {
        int cur = st & 1;
        if (st + 1 < NSTEP) {
            size_t ko = (size_t)(st + 1) * 32;
            gll16(gA0 + ko, &As[cur ^ 1][chunk0]);
            gll16(gA1 + ko, &As[cur ^ 1][chunk1]);
            gll16(gB0 + ko, &Bs[cur ^ 1][chunk0]);
            gll16(gB1 + ko, &Bs[cur ^ 1][chunk1]);
        }
        bf16x8 af[4], bfr[4];
        #pragma unroll
        for (int mi = 0; mi < 4; ++mi) {
            int r = wm * 64 + mi * 16 + rsub;
            int phys = r * 4 + (kq ^ ((r >> 1) & 3));
            af[mi] = *(const bf16x8*)&As[cur][phys * 8];
        }
        #pragma unroll
        for (int ni = 0; ni < 4; ++ni) {
            int r = wn * 64 + ni * 16 + rsub;
            int phys = r * 4 + (kq ^ ((r >> 1) & 3));
            bfr[ni] = *(const bf16x8*)&Bs[cur][phys * 8];
        }
        #pragma unroll
        for (int mi = 0; mi < 4; ++mi)
            #pragma unroll
            for (int ni = 0; ni < 4; ++ni)
                acc[mi][ni] = __builtin_amdgcn_mfma_f32_16x16x32_bf16(
                    af[mi], bfr[ni], acc[mi][ni], 0, 0, 0);
        __syncthreads();
    }
    #pragma unroll
    for (int mi = 0; mi < 4; ++mi) {
        int rowb = m0 + wm * 64 + mi * 16 + kq * 4;
        #pragma unroll
        for (int ni = 0; ni < 4; ++ni) {
            int col = n0 + wn * 64 + ni * 16 + rsub;
            int dcol = 2 + lvl * H2 + col;
            float bcol = bias[col];
            #pragma unroll
            for (int r = 0; r < 4; ++r) {
                int row = rowb + r;
                int sl = row >> 10, n = row & 1023;
                int s = s_begin + sl;
                out[((size_t)n * SN + s) * DOUT + dcol] =
                    acc[mi][ni][r] + bcol + te[s * DOUT + dcol];
            }
        }
    }
}

// ---------------------------------------------------------------------------
// Transpose + bf16-convert: in (K x Nw f32) -> out (Nw x Kp bf16), zero-pad.
// ---------------------------------------------------------------------------
__global__ __launch_bounds__(256) void conv_t_kernel(
    const float* __restrict__ in, unsigned short* __restrict__ outp,
    int K, int Nw, int Kp)
{
    __shared__ float tile[32][33];
    const int kb = blockIdx.x * 32, nb = blockIdx.y * 32;
    const int tx = threadIdx.x & 31, ty = threadIdx.x >> 5;
    #pragma unroll
    for (int i = 0; i < 32; i += 8) {
        int k = kb + ty + i, nn = nb + tx;
        tile[ty + i][tx] = (k < K && nn < Nw) ? in[(size_t)k * Nw + nn] : 0.f;
    }
    __syncthreads();
    #pragma unroll
    for (int i = 0; i < 32; i += 8) {
        int nn = nb + ty + i, k = kb + tx;
        if (nn < Nw) outp[(size_t)nn * Kp + k] = f2b(tile[tx][ty + i]);
    }
}

// Kernel D: vis, conf, rel_emb(84) + time_emb.
__global__ __launch_bounds__(128) void tail_kernel(
    const float* __restrict__ coords, const float* __restrict__ vis,
    const float* __restrict__ conf, const float* __restrict__ te,
    float* __restrict__ out)
{
    const int b = blockIdx.x;
    const int n = b >> 3, s = b & 7;
    const int d = threadIdx.x;
    if (d >= 86) return;
    const size_t ob = (size_t)b * DOUT;
    if (d == 0) {
        out[ob + 0] = vis[(size_t)s * NN + n] + te[s * DOUT + 0];
    } else if (d == 1) {
        out[ob + 1] = conf[(size_t)s * NN + n] + te[s * DOUT + 1];
    } else {
        int rd = d - 2;
        float cx = coords[((size_t)s * NN + n) * 2 + 0];
        float cy = coords[((size_t)s * NN + n) * 2 + 1];
        float rfx = 0.f, rfy = 0.f, rbx = 0.f, rby = 0.f;
        if (s < SN - 1) {
            rfx = cx - coords[((size_t)(s + 1) * NN + n) * 2 + 0];
            rfy = cy - coords[((size_t)(s + 1) * NN + n) * 2 + 1];
        }
        if (s > 0) {
            rbx = cx - coords[((size_t)(s - 1) * NN + n) * 2 + 0];
            rby = cy - coords[((size_t)(s - 1) * NN + n) * 2 + 1];
        }
        float r4[4] = {rfx / 128.f, rfy / 96.f, rbx / 128.f, rby / 96.f};
        float val;
        if (rd < 4) {
            val = r4[rd];
        } else if (rd < 44) {
            int q = rd - 4; int deg = q >> 2, comp = q & 3;
            val = sinf(r4[comp] * (float)(1 << deg));
        } else {
            int q = rd - 44; int deg = q >> 2, comp = q & 3;
            val = sinf(r4[comp] * (float)(1 << deg) + 1.57079632679489662f);
        }
        int od = 1026 + rd;
        out[ob + od] = val + te[s * DOUT + od];
    }
}

extern "C" void kernel_launch(void* const* d_in, const int* in_sizes, int n_in,
                              void* d_out, int out_size, void* d_ws, size_t ws_size,
                              hipStream_t stream) {
    const float* fmaps[4] = {(const float*)d_in[0], (const float*)d_in[2],
                             (const float*)d_in[4], (const float*)d_in[6]};
    const float* track[4] = {(const float*)d_in[1], (const float*)d_in[3],
                             (const float*)d_in[5], (const float*)d_in[7]};
    const float* coords = (const float*)d_in[8];
    const float* vis    = (const float*)d_in[9];
    const float* conf   = (const float*)d_in[10];
    const float* w1     = (const float*)d_in[11];
    const float* b1     = (const float*)d_in[12];
    const float* w2     = (const float*)d_in[13];
    const float* b2     = (const float*)d_in[14];
    const float* te     = (const float*)d_in[15];
    float* out = (float*)d_out;

    const int Hs[4] = {96, 48, 24, 12};
    const int Ws[4] = {128, 64, 32, 16};

    char* wsb = (char*)d_ws;
    unsigned short* w1t = (unsigned short*)wsb;                    // 384 x 2432
    unsigned short* w2t = (unsigned short*)(wsb + (size_t)H1 * K1P * 2);  // 256 x 384
    const size_t fixed = (size_t)H1 * K1P * 2 + (size_t)H2 * H1 * 2;
    int s_chunk = SN;
    while (s_chunk > 1 &&
           fixed + (size_t)s_chunk * NN * (K1P + H1) * 2 > ws_size)
        s_chunk >>= 1;
    unsigned short* volb = (unsigned short*)(wsb + fixed);
    unsigned short* hb   = volb + (size_t)s_chunk * NN * K1P;

    conv_t_kernel<<<dim3(K1P / 32, H1 / 32), 256, 0, stream>>>(w1, w1t, 2401, H1, K1P);
    conv_t_kernel<<<dim3(H1 / 32, H2 / 32), 256, 0, stream>>>(w2, w2t, H1, H2, H1);

    for (int lvl = 0; lvl < 4; ++lvl) {
        for (int s0 = 0; s0 < SN; s0 += s_chunk) {
            int rows = s_chunk * NN;
            sample_vol_kernel<<<NN, 256, 0, stream>>>(
                fmaps[lvl], track[lvl], coords, volb, Hs[lvl], Ws[lvl], lvl, s0, s_chunk);
            gemm1_kernel<<<dim3(rows / 128, 3), 256, 0, stream>>>(volb, w1t, b1, hb);
            gemm2_kernel<<<dim3(rows / 128, 2), 256, 0, stream>>>(hb, w2t, b2, te, out, s0, lvl);
        }
    }
    tail_kernel<<<SN * NN, 128, 0, stream>>>(coords, vis, conf, te, out);
}

// Round 3
// 668.132 us; speedup vs baseline: 3.9352x; 1.0414x over previous
//
#include <hip/hip_runtime.h>
#include <math.h>

// ---------------------------------------------------------------------------
// CoTracker correlation-embedding pipeline, bf16 MFMA, HWC-padded fmaps.
// B=1, S=8, N=1024, C=128, G=7, GG=49, K1=2401 (pad 2432), H1=384, H2=256.
// Inputs: 0:fmaps0 1:track0 2:fmaps1 3:track1 4:fmaps2 5:track2 6:fmaps3
//         7:track3 8:coords 9:vis 10:conf 11:w1 12:b1 13:w2 14:b2 15:time_emb
// Output: (1,N,8,1110) f32.
// ---------------------------------------------------------------------------

#define SN 8
#define NN 1024
#define CC 128
#define K1P 2432
#define H1 384
#define H2 256
#define DOUT 1110

typedef short bf16x8 __attribute__((ext_vector_type(8)));
typedef float f32x4 __attribute__((ext_vector_type(4)));

__device__ inline unsigned short f2b(float x) {  // RTNE f32 -> bf16
    union { float f; unsigned u; } v; v.f = x;
    unsigned r = v.u + 0x7FFFu + ((v.u >> 16) & 1u);
    return (unsigned short)(r >> 16);
}
__device__ inline float b2f(unsigned short u) {
    union { unsigned u; float f; } v; v.u = (unsigned)u << 16; return v.f;
}
__device__ inline void gll16(const void* g, void* l) {
    __builtin_amdgcn_global_load_lds(
        (const __attribute__((address_space(1))) void*)g,
        (__attribute__((address_space(3))) void*)l, 16, 0, 0);
}
// XOR-swizzled LDS layout for 64x128-short MFMA operand tiles (16B granules).
__device__ inline int swz(int row, int g) {
    return row * 128 + ((g ^ (row & 7)) << 3);
}

// ---------------------------------------------------------------------------
// fmap fp32 (S,C,H,W) -> bf16 HWC padded (S, H+8, W+8, C), border replicate.
// One block per (s, yp) row-plane; writes coalesced, reads L1-cached.
// ---------------------------------------------------------------------------
__global__ __launch_bounds__(256) void conv_fmap_kernel(
    const float* __restrict__ in, unsigned short* __restrict__ outp,
    int H, int W)
{
    const int Hp = H + 8, Wp = W + 8;
    const int s = blockIdx.x / Hp, yp = blockIdx.x % Hp;
    const int y = min(max(yp - 4, 0), H - 1);
    const float* src = in + (size_t)s * CC * H * W + (size_t)y * W;
    unsigned short* dst = outp + ((size_t)s * Hp + yp) * Wp * CC;
    for (int idx = threadIdx.x; idx < Wp * CC; idx += 256) {
        int xp = idx >> 7, c = idx & 127;
        int x = min(max(xp - 4, 0), W - 1);
        dst[idx] = f2b(src[(size_t)c * H * W + x]);
    }
}

// ---------------------------------------------------------------------------
// Kernel A: per-n block. trk loaded once (swizzled LDS). Per s:
//   patch (8y x 10x x 128c bf16) staged via global_load_lds (issued during
//   prev MFMA) -> bilinear -> samp (swizzled) -> MFMA 49x49x128 -> vol row.
// LDS 52.5KB -> 3 blocks/CU.
// ---------------------------------------------------------------------------
__global__ __launch_bounds__(256, 3) void sample_vol_kernel(
    const unsigned short* __restrict__ fpad, // (8, Hp, Wp, 128) bf16
    const float* __restrict__ track,         // (49, N, 128) f32
    const float* __restrict__ coords,        // (8, N, 2) f32
    unsigned short* __restrict__ vol,        // (s_count*N, 2432) bf16
    int Hp, int Wp, int lvl, int s_begin, int s_count)
{
    __shared__ __align__(16) unsigned short patch[8 * 10 * 128]; // 20.0 KB
    __shared__ __align__(16) unsigned short samp[64 * 128];      // 16 KB
    __shared__ __align__(16) unsigned short trk[64 * 128];       // 16 KB
    const int n = blockIdx.x, t = threadIdx.x;
    const int lane = t & 63, wv = t >> 6;
    const int rsub = lane & 15, kq = lane >> 4;
    const float inv = 1.0f / (float)(1 << lvl);
    const size_t plane = (size_t)Hp * Wp * CC;

    // per-lane static part of patch source offsets (shorts)
    int poff[5], ldso[5];
    #pragma unroll
    for (int i = 0; i < 5; ++i) {
        int task64 = wv * 5 + i;
        int point = task64 * 4 + (lane >> 4);  // 0..79
        int v = point / 10, xs = point - v * 10;
        poff[i] = (v * Wp + xs) * CC + (lane & 15) * 8;
        ldso[i] = task64 * 512;
    }

    // coords + first patch issue
    float cx = coords[((size_t)s_begin * NN + n) * 2 + 0] * inv;
    float cy = coords[((size_t)s_begin * NN + n) * 2 + 1] * inv;
    int fx = (int)floorf(cx), fy = (int)floorf(cy);
    int e = (fx - 3) & ~1;
    {
        const unsigned short* base =
            fpad + (size_t)s_begin * plane + ((fy + 1) * Wp + (e + 4)) * CC;
        #pragma unroll
        for (int i = 0; i < 5; ++i) gll16(base + poff[i], &patch[ldso[i]]);
    }
    // track[n] -> trk LDS (swizzled), once
    for (int task = t; task < 49 * 16; task += 256) {
        int row = task >> 4, g = task & 15;
        const float* srcp = &track[((size_t)row * NN + n) * CC + g * 8];
        float4 f0 = *(const float4*)srcp;
        float4 f1 = *(const float4*)(srcp + 4);
        bf16x8 v8;
        v8[0] = f2b(f0.x); v8[1] = f2b(f0.y); v8[2] = f2b(f0.z); v8[3] = f2b(f0.w);
        v8[4] = f2b(f1.x); v8[5] = f2b(f1.y); v8[6] = f2b(f1.z); v8[7] = f2b(f1.w);
        *(bf16x8*)&trk[swz(row, g)] = v8;
    }

    const int bc = t & 127, bp0 = t >> 7;

    for (int sl = 0; sl < s_count; ++sl) {
        // weights for current patch
        float wx = cx - (float)fx, wy = cy - (float)fy;
        float w00 = (1.f - wx) * (1.f - wy), w10 = wx * (1.f - wy);
        float w01 = (1.f - wx) * wy,         w11 = wx * wy;
        const int off = fx - 3 - e;

        asm volatile("s_waitcnt vmcnt(0)");
        __syncthreads();   // (a) patch landed everywhere; prev MFMA/samp done

        // ---- bilinear: samp[p][c] (swizzled), p = a*7+b ----
        {
            int a = 0, b = bp0;
            for (int p = bp0; p < 49; p += 2) {
                int r0 = (b * 10 + off + a) * CC + bc;
                int r1 = r0 + 10 * CC;
                float v = w00 * b2f(patch[r0])      + w10 * b2f(patch[r0 + CC])
                        + w01 * b2f(patch[r1])      + w11 * b2f(patch[r1 + CC]);
                samp[p * 128 + (((bc >> 3) ^ (p & 7)) << 3) + (bc & 7)] = f2b(v);
                b += 2; if (b >= 7) { b -= 7; ++a; }
            }
        }
        __syncthreads();   // (c) samp ready; patch consumed

        // ---- issue next-s patch loads (overlap with MFMA) ----
        if (sl + 1 < s_count) {
            int s2 = s_begin + sl + 1;
            cx = coords[((size_t)s2 * NN + n) * 2 + 0] * inv;
            cy = coords[((size_t)s2 * NN + n) * 2 + 1] * inv;
            fx = (int)floorf(cx); fy = (int)floorf(cy);
            e = (fx - 3) & ~1;
            const unsigned short* base =
                fpad + (size_t)s2 * plane + ((fy + 1) * Wp + (e + 4)) * CC;
            #pragma unroll
            for (int i = 0; i < 5; ++i) gll16(base + poff[i], &patch[ldso[i]]);
        }

        // ---- MFMA: 64x64 (49x49 used) ----
        {
            f32x4 acc[4] = {};
            #pragma unroll
            for (int kk = 0; kk < 4; ++kk) {
                bf16x8 a = *(const bf16x8*)&samp[swz(wv * 16 + rsub, kk * 4 + kq)];
                #pragma unroll
                for (int ni = 0; ni < 4; ++ni) {
                    bf16x8 b = *(const bf16x8*)&trk[swz(ni * 16 + rsub, kk * 4 + kq)];
                    acc[ni] = __builtin_amdgcn_mfma_f32_16x16x32_bf16(a, b, acc[ni], 0, 0, 0);
                }
            }
            unsigned short* vrow = vol + ((size_t)sl * NN + n) * K1P;
            #pragma unroll
            for (int ni = 0; ni < 4; ++ni) {
                #pragma unroll
                for (int r = 0; r < 4; ++r) {
                    int ab = wv * 16 + kq * 4 + r;
                    int ij = ni * 16 + rsub;
                    if (ab < 49 && ij < 49) vrow[ab * 49 + ij] = f2b(acc[ni][r]);
                }
            }
            if (t < 31) vrow[2401 + t] = 0;
        }
    }
}

// ---------------------------------------------------------------------------
// GEMM1: H = gelu(vol @ w1 + b1).  (rows x 2432) @ (2432 x 384) bf16.
// 1D grid, XCD-chunked m-major swizzle so the 3 n-tiles of one m-tile share
// an XCD's L2 (A fetched ~once).
// ---------------------------------------------------------------------------
__global__ __launch_bounds__(256) void gemm1_kernel(
    const unsigned short* __restrict__ A,   // rows x 2432
    const unsigned short* __restrict__ Bt,  // 384 x 2432 (= w1^T)
    const float* __restrict__ bias,
    unsigned short* __restrict__ Hout)      // rows x 384
{
    __shared__ __align__(16) unsigned short As[2][128 * 32];
    __shared__ __align__(16) unsigned short Bs[2][128 * 32];
    const int h = blockIdx.x, q = gridDim.x >> 3;
    const int l = (h & 7) * q + (h >> 3);
    const int m0 = (l / 3) * 128, n0 = (l % 3) * 128;
    const int t = threadIdx.x, lane = t & 63, wv = t >> 6;
    const int wm = wv >> 1, wn = wv & 1;
    const int rsub = lane & 15, kq = lane >> 4;

    const int rA0 = t >> 2, sA0 = (t & 3) ^ ((rA0 >> 1) & 3);
    const int rA1 = (t + 256) >> 2, sA1 = ((t + 256) & 3) ^ ((rA1 >> 1) & 3);
    const unsigned short* gA0 = A  + (size_t)(m0 + rA0) * K1P + sA0 * 8;
    const unsigned short* gA1 = A  + (size_t)(m0 + rA1) * K1P + sA1 * 8;
    const unsigned short* gB0 = Bt + (size_t)(n0 + rA0) * K1P + sA0 * 8;
    const unsigned short* gB1 = Bt + (size_t)(n0 + rA1) * K1P + sA1 * 8;
    const int chunk0 = (t & ~63) * 8, chunk1 = (256 + (t & ~63)) * 8;

    f32x4 acc[4][4] = {};

    gll16(gA0, &As[0][chunk0]); gll16(gA1, &As[0][chunk1]);
    gll16(gB0, &Bs[0][chunk0]); gll16(gB1, &Bs[0][chunk1]);
    __syncthreads();

    const int NSTEP = K1P / 32;  // 76
    for (int st = 0; st < NSTEP; ++st) {
        int cur = st & 1;
        if (st + 1 < NSTEP) {
            size_t ko = (size_t)(st + 1) * 32;
            gll16(gA0 + ko, &As[cur ^ 1][chunk0]);
            gll16(gA1 + ko, &As[cur ^ 1][chunk1]);
            gll16(gB0 + ko, &Bs[cur ^ 1][chunk0]);
            gll16(gB1 + ko, &Bs[cur ^ 1][chunk1]);
        }
        bf16x8 af[4], bfr[4];
        #pragma unroll
        for (int mi = 0; mi < 4; ++mi) {
            int r = wm * 64 + mi * 16 + rsub;
            int phys = r * 4 + (kq ^ ((r >> 1) & 3));
            af[mi] = *(const bf16x8*)&As[cur][phys * 8];
        }
        #pragma unroll
        for (int ni = 0; ni < 4; ++ni) {
            int r = wn * 64 + ni * 16 + rsub;
            int phys = r * 4 + (kq ^ ((r >> 1) & 3));
            bfr[ni] = *(const bf16x8*)&Bs[cur][phys * 8];
        }
        #pragma unroll
        for (int mi = 0; mi < 4; ++mi)
            #pragma unroll
            for (int ni = 0; ni < 4; ++ni)
                acc[mi][ni] = __builtin_amdgcn_mfma_f32_16x16x32_bf16(
                    af[mi], bfr[ni], acc[mi][ni], 0, 0, 0);
        __syncthreads();
    }
    #pragma unroll
    for (int mi = 0; mi < 4; ++mi) {
        int row = m0 + wm * 64 + mi * 16 + kq * 4;
        #pragma unroll
        for (int ni = 0; ni < 4; ++ni) {
            int col = n0 + wn * 64 + ni * 16 + rsub;
            float bcol = bias[col];
            #pragma unroll
            for (int r = 0; r < 4; ++r) {
                float x = acc[mi][ni][r] + bcol;
                float g = 0.5f * x * (1.f + erff(x * 0.70710678118654752f));
                Hout[(size_t)(row + r) * H1 + col] = f2b(g);
            }
        }
    }
}

// ---------------------------------------------------------------------------
// GEMM2: out slice = H @ w2 + b2 + time_emb.  (rows x 384) @ (384 x 256).
// ---------------------------------------------------------------------------
__global__ __launch_bounds__(256) void gemm2_kernel(
    const unsigned short* __restrict__ A,   // rows x 384
    const unsigned short* __restrict__ Bt,  // 256 x 384 (= w2^T)
    const float* __restrict__ bias,
    const float* __restrict__ te,           // (8, 1110)
    float* __restrict__ out,                // (N, 8, 1110)
    int s_begin, int lvl)
{
    __shared__ __align__(16) unsigned short As[2][128 * 32];
    __shared__ __align__(16) unsigned short Bs[2][128 * 32];
    const int h = blockIdx.x, q = gridDim.x >> 3;
    const int l = (h & 7) * q + (h >> 3);
    const int m0 = (l >> 1) * 128, n0 = (l & 1) * 128;
    const int t = threadIdx.x, lane = t & 63, wv = t >> 6;
    const int wm = wv >> 1, wn = wv & 1;
    const int rsub = lane & 15, kq = lane >> 4;

    const int rA0 = t >> 2, sA0 = (t & 3) ^ ((rA0 >> 1) & 3);
    const int rA1 = (t + 256) >> 2, sA1 = ((t + 256) & 3) ^ ((rA1 >> 1) & 3);
    const unsigned short* gA0 = A  + (size_t)(m0 + rA0) * H1 + sA0 * 8;
    const unsigned short* gA1 = A  + (size_t)(m0 + rA1) * H1 + sA1 * 8;
    const unsigned short* gB0 = Bt + (size_t)(n0 + rA0) * H1 + sA0 * 8;
    const unsigned short* gB1 = Bt + (size_t)(n0 + rA1) * H1 + sA1 * 8;
    const int chunk0 = (t & ~63) * 8, chunk1 = (256 + (t & ~63)) * 8;

    f32x4 acc[4][4] = {};

    gll16(gA0, &As[0][chunk0]); gll16(gA1, &As[0][chunk1]);
    gll16(gB0, &Bs[0][chunk0]); gll16(gB1, &Bs[0][chunk1]);
    __syncthreads();

    const int NSTEP = H1 / 32;  // 12
    for (int st = 0; st < NSTEP; ++st) {
        int cur = st & 1;
        if (st + 1 < NSTEP) {
            size_t ko = (size_t)(st + 1) * 32;
            gll16(gA0 + ko, &As[cur ^ 1][chunk0]);
            gll16(gA1 + ko, &As[cur ^ 1][chunk1]);
            gll16(gB0 + ko, &Bs[cur ^ 1][chunk0]);
            gll16(gB1 + ko, &Bs[cur ^ 1][chunk1]);
        }
        bf16x8 af[4], bfr[4];
        #pragma unroll
        for (int mi = 0; mi < 4; ++mi) {
            int r = wm * 64 + mi * 16 + rsub;
            int phys = r * 4 + (kq ^ ((r >> 1) & 3));
            af[mi] = *(const bf16x8*)&As[cur][phys * 8];
        }
        #pragma unroll
        for (int ni = 0; ni < 4; ++ni) {
            int r = wn * 64 + ni * 16 + rsub;
            int phys = r * 4 + (kq ^ ((r >> 1) & 3));
            bfr[ni] = *(const bf16x8*)&Bs[cur][phys * 8];
        }
        #pragma unroll
        for (int mi = 0; mi < 4; ++mi)
            #pragma unroll
            for (int ni = 0; ni < 4; ++ni)
                acc[mi][ni] = __builtin_amdgcn_mfma_f32_16x16x32_bf16(
                    af[mi], bfr[ni], acc[mi][ni], 0, 0, 0);
        __syncthreads();
    }
    #pragma unroll
    for (int mi = 0; mi < 4; ++mi) {
        int rowb = m0 + wm * 64 + mi * 16 + kq * 4;
        #pragma unroll
        for (int ni = 0; ni < 4; ++ni) {
            int col = n0 + wn * 64 + ni * 16 + rsub;
            int dcol = 2 + lvl * H2 + col;
            float bcol = bias[col];
            #pragma unroll
            for (int r = 0; r < 4; ++r) {
                int row = rowb + r;
                int sl = row >> 10, n = row & 1023;
                int s = s_begin + sl;
                out[((size_t)n * SN + s) * DOUT + dcol] =
                    acc[mi][ni][r] + bcol + te[s * DOUT + dcol];
            }
        }
    }
}

// ---------------------------------------------------------------------------
// Transpose + bf16-convert: in (K x Nw f32) -> out (Nw x Kp bf16), zero-pad.
// ---------------------------------------------------------------------------
__global__ __launch_bounds__(256) void conv_t_kernel(
    const float* __restrict__ in, unsigned short* __restrict__ outp,
    int K, int Nw, int Kp)
{
    __shared__ float tile[32][33];
    const int kb = blockIdx.x * 32, nb = blockIdx.y * 32;
    const int tx = threadIdx.x & 31, ty = threadIdx.x >> 5;
    #pragma unroll
    for (int i = 0; i < 32; i += 8) {
        int k = kb + ty + i, nn = nb + tx;
        tile[ty + i][tx] = (k < K && nn < Nw) ? in[(size_t)k * Nw + nn] : 0.f;
    }
    __syncthreads();
    #pragma unroll
    for (int i = 0; i < 32; i += 8) {
        int nn = nb + ty + i, k = kb + tx;
        if (nn < Nw) outp[(size_t)nn * Kp + k] = f2b(tile[tx][ty + i]);
    }
}

// Kernel D: vis, conf, rel_emb(84) + time_emb.
__global__ __launch_bounds__(128) void tail_kernel(
    const float* __restrict__ coords, const float* __restrict__ vis,
    const float* __restrict__ conf, const float* __restrict__ te,
    float* __restrict__ out)
{
    const int b = blockIdx.x;
    const int n = b >> 3, s = b & 7;
    const int d = threadIdx.x;
    if (d >= 86) return;
    const size_t ob = (size_t)b * DOUT;
    if (d == 0) {
        out[ob + 0] = vis[(size_t)s * NN + n] + te[s * DOUT + 0];
    } else if (d == 1) {
        out[ob + 1] = conf[(size_t)s * NN + n] + te[s * DOUT + 1];
    } else {
        int rd = d - 2;
        float cx = coords[((size_t)s * NN + n) * 2 + 0];
        float cy = coords[((size_t)s * NN + n) * 2 + 1];
        float rfx = 0.f, rfy = 0.f, rbx = 0.f, rby = 0.f;
        if (s < SN - 1) {
            rfx = cx - coords[((size_t)(s + 1) * NN + n) * 2 + 0];
            rfy = cy - coords[((size_t)(s + 1) * NN + n) * 2 + 1];
        }
        if (s > 0) {
            rbx = cx - coords[((size_t)(s - 1) * NN + n) * 2 + 0];
            rby = cy - coords[((size_t)(s - 1) * NN + n) * 2 + 1];
        }
        float r4[4] = {rfx / 128.f, rfy / 96.f, rbx / 128.f, rby / 96.f};
        float val;
        if (rd < 4) {
            val = r4[rd];
        } else if (rd < 44) {
            int q = rd - 4; int deg = q >> 2, comp = q & 3;
            val = sinf(r4[comp] * (float)(1 << deg));
        } else {
            int q = rd - 44; int deg = q >> 2, comp = q & 3;
            val = sinf(r4[comp] * (float)(1 << deg) + 1.57079632679489662f);
        }
        int od = 1026 + rd;
        out[ob + od] = val + te[s * DOUT + od];
    }
}

extern "C" void kernel_launch(void* const* d_in, const int* in_sizes, int n_in,
                              void* d_out, int out_size, void* d_ws, size_t ws_size,
                              hipStream_t stream) {
    const float* fmaps[4] = {(const float*)d_in[0], (const float*)d_in[2],
                             (const float*)d_in[4], (const float*)d_in[6]};
    const float* track[4] = {(const float*)d_in[1], (const float*)d_in[3],
                             (const float*)d_in[5], (const float*)d_in[7]};
    const float* coords = (const float*)d_in[8];
    const float* vis    = (const float*)d_in[9];
    const float* conf   = (const float*)d_in[10];
    const float* w1     = (const float*)d_in[11];
    const float* b1     = (const float*)d_in[12];
    const float* w2     = (const float*)d_in[13];
    const float* b2     = (const float*)d_in[14];
    const float* te     = (const float*)d_in[15];
    float* out = (float*)d_out;

    const int Hs[4] = {96, 48, 24, 12};
    const int Ws[4] = {128, 64, 32, 16};

    // ---- workspace layout ----
    char* wsb = (char*)d_ws;
    unsigned short* w1t = (unsigned short*)wsb;
    size_t off = (size_t)H1 * K1P * 2;
    unsigned short* w2t = (unsigned short*)(wsb + off);
    off += (size_t)H2 * H1 * 2;
    unsigned short* fpad[4];
    for (int l = 0; l < 4; ++l) {
        fpad[l] = (unsigned short*)(wsb + off);
        off += (size_t)SN * (Hs[l] + 8) * (Ws[l] + 8) * CC * 2;
    }
    off += 512;  // slack for benign over-reads
    const size_t fixed = off;
    int s_chunk = SN;
    while (s_chunk > 1 &&
           fixed + (size_t)s_chunk * NN * (K1P + H1) * 2 > ws_size)
        s_chunk >>= 1;
    unsigned short* volb = (unsigned short*)(wsb + fixed);
    unsigned short* hb   = volb + (size_t)s_chunk * NN * K1P;

    // ---- weight prep + fmap conversion ----
    conv_t_kernel<<<dim3(K1P / 32, H1 / 32), 256, 0, stream>>>(w1, w1t, 2401, H1, K1P);
    conv_t_kernel<<<dim3(H1 / 32, H2 / 32), 256, 0, stream>>>(w2, w2t, H1, H2, H1);
    for (int l = 0; l < 4; ++l)
        conv_fmap_kernel<<<SN * (Hs[l] + 8), 256, 0, stream>>>(
            fmaps[l], fpad[l], Hs[l], Ws[l]);

    for (int lvl = 0; lvl < 4; ++lvl) {
        for (int s0 = 0; s0 < SN; s0 += s_chunk) {
            int rows = s_chunk * NN;
            sample_vol_kernel<<<NN, 256, 0, stream>>>(
                fpad[lvl], track[lvl], coords, volb,
                Hs[lvl] + 8, Ws[lvl] + 8, lvl, s0, s_chunk);
            gemm1_kernel<<<(rows / 128) * 3, 256, 0, stream>>>(volb, w1t, b1, hb);
            gemm2_kernel<<<(rows / 128) * 2, 256, 0, stream>>>(hb, w2t, b2, te, out, s0, lvl);
        }
    }
    tail_kernel<<<SN * NN, 128, 0, stream>>>(coords, vis, conf, te, out);
}

// Round 4
// 583.664 us; speedup vs baseline: 4.5047x; 1.1447x over previous
//
#include <hip/hip_runtime.h>
#include <math.h>

// ---------------------------------------------------------------------------
// CoTracker correlation-embedding pipeline, bf16 MFMA, HWC-padded fmaps.
// Round 3: sample_vol computes patch-correlation via MFMA FIRST (80x49x128),
// then bilinear on the 49x49 output domain (linearity), killing the per-
// channel scalar-LDS bilinear and the scattered b16 global stores.
// Inputs: 0:fmaps0 1:track0 2:fmaps1 3:track1 4:fmaps2 5:track2 6:fmaps3
//         7:track3 8:coords 9:vis 10:conf 11:w1 12:b1 13:w2 14:b2 15:time_emb
// Output: (1,N,8,1110) f32.
// ---------------------------------------------------------------------------

#define SN 8
#define NN 1024
#define CC 128
#define K1P 2432
#define H1 384
#define H2 256
#define DOUT 1110

typedef short bf16x8 __attribute__((ext_vector_type(8)));
typedef float f32x4 __attribute__((ext_vector_type(4)));

__device__ inline unsigned short f2b(float x) {  // RTNE f32 -> bf16
    union { float f; unsigned u; } v; v.f = x;
    unsigned r = v.u + 0x7FFFu + ((v.u >> 16) & 1u);
    return (unsigned short)(r >> 16);
}
__device__ inline float b2f(unsigned short u) {
    union { unsigned u; float f; } v; v.u = (unsigned)u << 16; return v.f;
}
__device__ inline void gll16(const void* g, void* l) {
    __builtin_amdgcn_global_load_lds(
        (const __attribute__((address_space(1))) void*)g,
        (__attribute__((address_space(3))) void*)l, 16, 0, 0);
}
// XOR-swizzled LDS index (shorts) for [rows][128] bf16 MFMA operand tiles.
__device__ inline int swz(int row, int g) {
    return row * 128 + ((g ^ (row & 7)) << 3);
}

// ---------------------------------------------------------------------------
// fmap fp32 (S,C,H,W) -> bf16 HWC padded (S, H+8, W+8, C), border replicate.
// ---------------------------------------------------------------------------
__global__ __launch_bounds__(256) void conv_fmap_kernel(
    const float* __restrict__ in, unsigned short* __restrict__ outp,
    int H, int W)
{
    const int Hp = H + 8, Wp = W + 8;
    const int s = blockIdx.x / Hp, yp = blockIdx.x % Hp;
    const int y = min(max(yp - 4, 0), H - 1);
    const float* src = in + (size_t)s * CC * H * W + (size_t)y * W;
    unsigned short* dst = outp + ((size_t)s * Hp + yp) * Wp * CC;
    for (int idx = threadIdx.x; idx < Wp * CC; idx += 256) {
        int xp = idx >> 7, c = idx & 127;
        int x = min(max(xp - 4, 0), W - 1);
        dst[idx] = f2b(src[(size_t)c * H * W + x]);
    }
}

// ---------------------------------------------------------------------------
// Kernel A: per-n block. trk loaded once (swizzled). Per s:
//   patch (8y x 10x x 128c bf16, swizzled via pre-swizzled global src) staged
//   by global_load_lds (prefetched during prev bilinear) ->
//   MFMA pc[80][49] = patch . trk -> LDS ->
//   bilinear on output domain -> vol row (packed b32, coalesced).
// LDS 58.6KB -> 2 blocks/CU.
// ---------------------------------------------------------------------------
__global__ __launch_bounds__(256, 2) void sample_vol_kernel(
    const unsigned short* __restrict__ fpad, // (8, Hp, Wp, 128) bf16
    const float* __restrict__ track,         // (49, N, 128) f32
    const float* __restrict__ coords,        // (8, N, 2) f32
    unsigned short* __restrict__ vol,        // (s_count*N, 2432) bf16
    int Hp, int Wp, int lvl, int s_begin, int s_count)
{
    __shared__ __align__(16) unsigned short patch[80 * 128];  // 20.0 KB
    __shared__ __align__(16) unsigned short trk[64 * 128];    // 16 KB
    __shared__ __align__(16) float pcL[80 * 68];              // 21.75 KB
    const int n = blockIdx.x, t = threadIdx.x;
    const int lane = t & 63, wv = t >> 6;
    const int rsub = lane & 15, kq = lane >> 4;
    const float inv = 1.0f / (float)(1 << lvl);
    const size_t plane = (size_t)Hp * Wp * CC;

    // per-lane static patch-load offsets; global granule pre-swizzled so the
    // linear global_load_lds dest yields physical granule g = logical^(row&7)
    int poff[5], ldso[5];
    #pragma unroll
    for (int i = 0; i < 5; ++i) {
        int task64 = wv * 5 + i;
        int point = task64 * 4 + (lane >> 4);  // patch row 0..79
        int v = point / 10, xs = point - v * 10;
        int j = (lane & 15) ^ (point & 7);     // logical granule to fetch
        poff[i] = (v * Wp + xs) * CC + j * 8;
        ldso[i] = task64 * 512;                // shorts; 1KB per task
    }

    // coords + first patch issue
    float cx = coords[((size_t)s_begin * NN + n) * 2 + 0] * inv;
    float cy = coords[((size_t)s_begin * NN + n) * 2 + 1] * inv;
    int fx = (int)floorf(cx), fy = (int)floorf(cy);
    int e = (fx - 3) & ~1;
    {
        const unsigned short* base =
            fpad + (size_t)s_begin * plane + ((fy + 1) * Wp + (e + 4)) * CC;
        #pragma unroll
        for (int i = 0; i < 5; ++i) gll16(base + poff[i], &patch[ldso[i]]);
    }
    // track[n] -> trk LDS (swizzled), once
    for (int task = t; task < 49 * 16; task += 256) {
        int row = task >> 4, g = task & 15;
        const float* srcp = &track[((size_t)row * NN + n) * CC + g * 8];
        float4 f0 = *(const float4*)srcp;
        float4 f1 = *(const float4*)(srcp + 4);
        bf16x8 v8;
        v8[0] = f2b(f0.x); v8[1] = f2b(f0.y); v8[2] = f2b(f0.z); v8[3] = f2b(f0.w);
        v8[4] = f2b(f1.x); v8[5] = f2b(f1.y); v8[6] = f2b(f1.z); v8[7] = f2b(f1.w);
        *(bf16x8*)&trk[swz(row, g)] = v8;
    }

    for (int sl = 0; sl < s_count; ++sl) {
        // current-s bilinear weights (must be read before prefetch overwrites)
        const float wx = cx - (float)fx, wy = cy - (float)fy;
        const float w00 = (1.f - wx) * (1.f - wy), w10 = wx * (1.f - wy);
        const float w01 = (1.f - wx) * wy,         w11 = wx * wy;
        const int off = fx - 3 - e;

        asm volatile("s_waitcnt vmcnt(0)");
        __syncthreads();   // patch landed; prev bilinear readers of pcL done

        // ---- MFMA: pc[80][64] = patch(80x128) . trk(64x128)^T ----
        {
            f32x4 acc[5] = {};
            #pragma unroll
            for (int kk = 0; kk < 4; ++kk) {
                int gg = kk * 4 + kq;
                bf16x8 b = *(const bf16x8*)&trk[swz(wv * 16 + rsub, gg)];
                #pragma unroll
                for (int ti = 0; ti < 5; ++ti) {
                    int row = ti * 16 + rsub;
                    bf16x8 a = *(const bf16x8*)&patch[swz(row, gg)];
                    acc[ti] = __builtin_amdgcn_mfma_f32_16x16x32_bf16(a, b, acc[ti], 0, 0, 0);
                }
            }
            #pragma unroll
            for (int ti = 0; ti < 5; ++ti)
                #pragma unroll
                for (int r = 0; r < 4; ++r)
                    pcL[(ti * 16 + kq * 4 + r) * 68 + wv * 16 + rsub] = acc[ti][r];
        }
        __syncthreads();   // pc ready; patch consumed

        // ---- issue next-s patch loads (overlap with bilinear) ----
        if (sl + 1 < s_count) {
            int s2 = s_begin + sl + 1;
            cx = coords[((size_t)s2 * NN + n) * 2 + 0] * inv;
            cy = coords[((size_t)s2 * NN + n) * 2 + 1] * inv;
            fx = (int)floorf(cx); fy = (int)floorf(cy);
            e = (fx - 3) & ~1;
            const unsigned short* base =
                fpad + (size_t)s2 * plane + ((fy + 1) * Wp + (e + 4)) * CC;
            #pragma unroll
            for (int i = 0; i < 5; ++i) gll16(base + poff[i], &patch[ldso[i]]);
        }

        // ---- bilinear on output domain; packed b32 coalesced stores ----
        {
            unsigned* vrow32 = (unsigned*)(vol + ((size_t)sl * NN + n) * K1P);
            for (int d = t; d < K1P / 2; d += 256) {
                int s0 = 2 * d;
                unsigned pk = 0;
                if (s0 < 2401) {
                    int ab0 = s0 / 49, ij0 = s0 - 49 * ab0;
                    int a0 = ab0 / 7, b0 = ab0 - 7 * a0;
                    int p0 = b0 * 10 + off + a0;
                    const float* q = &pcL[p0 * 68 + ij0];
                    float v0 = w00 * q[0] + w10 * q[68] + w01 * q[680] + w11 * q[748];
                    unsigned short lo = f2b(v0), hi = 0;
                    int s1 = s0 + 1;
                    if (s1 < 2401) {
                        int ab1 = ab0, ij1 = ij0 + 1;
                        if (ij1 == 49) { ij1 = 0; ab1 = ab0 + 1; }
                        int a1 = ab1 / 7, b1 = ab1 - 7 * a1;
                        int p1 = b1 * 10 + off + a1;
                        const float* q1 = &pcL[p1 * 68 + ij1];
                        float v1 = w00 * q1[0] + w10 * q1[68] + w01 * q1[680] + w11 * q1[748];
                        hi = f2b(v1);
                    }
                    pk = (unsigned)lo | ((unsigned)hi << 16);
                }
                vrow32[d] = pk;
            }
        }
    }
}

// ---------------------------------------------------------------------------
// GEMM1: H = gelu(vol @ w1 + b1).  (rows x 2432) @ (2432 x 384) bf16.
// ---------------------------------------------------------------------------
__global__ __launch_bounds__(256) void gemm1_kernel(
    const unsigned short* __restrict__ A,   // rows x 2432
    const unsigned short* __restrict__ Bt,  // 384 x 2432 (= w1^T)
    const float* __restrict__ bias,
    unsigned short* __restrict__ Hout)      // rows x 384
{
    __shared__ __align__(16) unsigned short As[2][128 * 32];
    __shared__ __align__(16) unsigned short Bs[2][128 * 32];
    const int h = blockIdx.x, q = gridDim.x >> 3;
    const int l = (h & 7) * q + (h >> 3);
    const int m0 = (l / 3) * 128, n0 = (l % 3) * 128;
    const int t = threadIdx.x, lane = t & 63, wv = t >> 6;
    const int wm = wv >> 1, wn = wv & 1;
    const int rsub = lane & 15, kq = lane >> 4;

    const int rA0 = t >> 2, sA0 = (t & 3) ^ ((rA0 >> 1) & 3);
    const int rA1 = (t + 256) >> 2, sA1 = ((t + 256) & 3) ^ ((rA1 >> 1) & 3);
    const unsigned short* gA0 = A  + (size_t)(m0 + rA0) * K1P + sA0 * 8;
    const unsigned short* gA1 = A  + (size_t)(m0 + rA1) * K1P + sA1 * 8;
    const unsigned short* gB0 = Bt + (size_t)(n0 + rA0) * K1P + sA0 * 8;
    const unsigned short* gB1 = Bt + (size_t)(n0 + rA1) * K1P + sA1 * 8;
    const int chunk0 = (t & ~63) * 8, chunk1 = (256 + (t & ~63)) * 8;

    f32x4 acc[4][4] = {};

    gll16(gA0, &As[0][chunk0]); gll16(gA1, &As[0][chunk1]);
    gll16(gB0, &Bs[0][chunk0]); gll16(gB1, &Bs[0][chunk1]);
    __syncthreads();

    const int NSTEP = K1P / 32;  // 76
    for (int st = 0; st < NSTEP; ++st) {
        int cur = st & 1;
        if (st + 1 < NSTEP) {
            size_t ko = (size_t)(st + 1) * 32;
            gll16(gA0 + ko, &As[cur ^ 1][chunk0]);
            gll16(gA1 + ko, &As[cur ^ 1][chunk1]);
            gll16(gB0 + ko, &Bs[cur ^ 1][chunk0]);
            gll16(gB1 + ko, &Bs[cur ^ 1][chunk1]);
        }
        bf16x8 af[4], bfr[4];
        #pragma unroll
        for (int mi = 0; mi < 4; ++mi) {
            int r = wm * 64 + mi * 16 + rsub;
            int phys = r * 4 + (kq ^ ((r >> 1) & 3));
            af[mi] = *(const bf16x8*)&As[cur][phys * 8];
        }
        #pragma unroll
        for (int ni = 0; ni < 4; ++ni) {
            int r = wn * 64 + ni * 16 + rsub;
            int phys = r * 4 + (kq ^ ((r >> 1) & 3));
            bfr[ni] = *(const bf16x8*)&Bs[cur][phys * 8];
        }
        #pragma unroll
        for (int mi = 0; mi < 4; ++mi)
            #pragma unroll
            for (int ni = 0; ni < 4; ++ni)
                acc[mi][ni] = __builtin_amdgcn_mfma_f32_16x16x32_bf16(
                    af[mi], bfr[ni], acc[mi][ni], 0, 0, 0);
        __syncthreads();
    }
    #pragma unroll
    for (int mi = 0; mi < 4; ++mi) {
        int row = m0 + wm * 64 + mi * 16 + kq * 4;
        #pragma unroll
        for (int ni = 0; ni < 4; ++ni) {
            int col = n0 + wn * 64 + ni * 16 + rsub;
            float bcol = bias[col];
            #pragma unroll
            for (int r = 0; r < 4; ++r) {
                float x = acc[mi][ni][r] + bcol;
                float g = 0.5f * x * (1.f + erff(x * 0.70710678118654752f));
                Hout[(size_t)(row + r) * H1 + col] = f2b(g);
            }
        }
    }
}

// ---------------------------------------------------------------------------
// GEMM2: out slice = H @ w2 + b2 + time_emb.  (rows x 384) @ (384 x 256).
// ---------------------------------------------------------------------------
__global__ __launch_bounds__(256) void gemm2_kernel(
    const unsigned short* __restrict__ A,   // rows x 384
    const unsigned short* __restrict__ Bt,  // 256 x 384 (= w2^T)
    const float* __restrict__ bias,
    const float* __restrict__ te,           // (8, 1110)
    float* __restrict__ out,                // (N, 8, 1110)
    int s_begin, int lvl)
{
    __shared__ __align__(16) unsigned short As[2][128 * 32];
    __shared__ __align__(16) unsigned short Bs[2][128 * 32];
    const int h = blockIdx.x, q = gridDim.x >> 3;
    const int l = (h & 7) * q + (h >> 3);
    const int m0 = (l >> 1) * 128, n0 = (l & 1) * 128;
    const int t = threadIdx.x, lane = t & 63, wv = t >> 6;
    const int wm = wv >> 1, wn = wv & 1;
    const int rsub = lane & 15, kq = lane >> 4;

    const int rA0 = t >> 2, sA0 = (t & 3) ^ ((rA0 >> 1) & 3);
    const int rA1 = (t + 256) >> 2, sA1 = ((t + 256) & 3) ^ ((rA1 >> 1) & 3);
    const unsigned short* gA0 = A  + (size_t)(m0 + rA0) * H1 + sA0 * 8;
    const unsigned short* gA1 = A  + (size_t)(m0 + rA1) * H1 + sA1 * 8;
    const unsigned short* gB0 = Bt + (size_t)(n0 + rA0) * H1 + sA0 * 8;
    const unsigned short* gB1 = Bt + (size_t)(n0 + rA1) * H1 + sA1 * 8;
    const int chunk0 = (t & ~63) * 8, chunk1 = (256 + (t & ~63)) * 8;

    f32x4 acc[4][4] = {};

    gll16(gA0, &As[0][chunk0]); gll16(gA1, &As[0][chunk1]);
    gll16(gB0, &Bs[0][chunk0]); gll16(gB1, &Bs[0][chunk1]);
    __syncthreads();

    const int NSTEP = H1 / 32;  // 12
    for (int st = 0; st < NSTEP; ++st) {
        int cur = st & 1;
        if (st + 1 < NSTEP) {
            size_t ko = (size_t)(st + 1) * 32;
            gll16(gA0 + ko, &As[cur ^ 1][chunk0]);
            gll16(gA1 + ko, &As[cur ^ 1][chunk1]);
            gll16(gB0 + ko, &Bs[cur ^ 1][chunk0]);
            gll16(gB1 + ko, &Bs[cur ^ 1][chunk1]);
        }
        bf16x8 af[4], bfr[4];
        #pragma unroll
        for (int mi = 0; mi < 4; ++mi) {
            int r = wm * 64 + mi * 16 + rsub;
            int phys = r * 4 + (kq ^ ((r >> 1) & 3));
            af[mi] = *(const bf16x8*)&As[cur][phys * 8];
        }
        #pragma unroll
        for (int ni = 0; ni < 4; ++ni) {
            int r = wn * 64 + ni * 16 + rsub;
            int phys = r * 4 + (kq ^ ((r >> 1) & 3));
            bfr[ni] = *(const bf16x8*)&Bs[cur][phys * 8];
        }
        #pragma unroll
        for (int mi = 0; mi < 4; ++mi)
            #pragma unroll
            for (int ni = 0; ni < 4; ++ni)
                acc[mi][ni] = __builtin_amdgcn_mfma_f32_16x16x32_bf16(
                    af[mi], bfr[ni], acc[mi][ni], 0, 0, 0);
        __syncthreads();
    }
    #pragma unroll
    for (int mi = 0; mi < 4; ++mi) {
        int rowb = m0 + wm * 64 + mi * 16 + kq * 4;
        #pragma unroll
        for (int ni = 0; ni < 4; ++ni) {
            int col = n0 + wn * 64 + ni * 16 + rsub;
            int dcol = 2 + lvl * H2 + col;
            float bcol = bias[col];
            #pragma unroll
            for (int r = 0; r < 4; ++r) {
                int row = rowb + r;
                int sl = row >> 10, n = row & 1023;
                int s = s_begin + sl;
                out[((size_t)n * SN + s) * DOUT + dcol] =
                    acc[mi][ni][r] + bcol + te[s * DOUT + dcol];
            }
        }
    }
}

// ---------------------------------------------------------------------------
// Transpose + bf16-convert: in (K x Nw f32) -> out (Nw x Kp bf16), zero-pad.
// ---------------------------------------------------------------------------
__global__ __launch_bounds__(256) void conv_t_kernel(
    const float* __restrict__ in, unsigned short* __restrict__ outp,
    int K, int Nw, int Kp)
{
    __shared__ float tile[32][33];
    const int kb = blockIdx.x * 32, nb = blockIdx.y * 32;
    const int tx = threadIdx.x & 31, ty = threadIdx.x >> 5;
    #pragma unroll
    for (int i = 0; i < 32; i += 8) {
        int k = kb + ty + i, nn = nb + tx;
        tile[ty + i][tx] = (k < K && nn < Nw) ? in[(size_t)k * Nw + nn] : 0.f;
    }
    __syncthreads();
    #pragma unroll
    for (int i = 0; i < 32; i += 8) {
        int nn = nb + ty + i, k = kb + tx;
        if (nn < Nw) outp[(size_t)nn * Kp + k] = f2b(tile[tx][ty + i]);
    }
}

// Kernel D: vis, conf, rel_emb(84) + time_emb.
__global__ __launch_bounds__(128) void tail_kernel(
    const float* __restrict__ coords, const float* __restrict__ vis,
    const float* __restrict__ conf, const float* __restrict__ te,
    float* __restrict__ out)
{
    const int b = blockIdx.x;
    const int n = b >> 3, s = b & 7;
    const int d = threadIdx.x;
    if (d >= 86) return;
    const size_t ob = (size_t)b * DOUT;
    if (d == 0) {
        out[ob + 0] = vis[(size_t)s * NN + n] + te[s * DOUT + 0];
    } else if (d == 1) {
        out[ob + 1] = conf[(size_t)s * NN + n] + te[s * DOUT + 1];
    } else {
        int rd = d - 2;
        float cx = coords[((size_t)s * NN + n) * 2 + 0];
        float cy = coords[((size_t)s * NN + n) * 2 + 1];
        float rfx = 0.f, rfy = 0.f, rbx = 0.f, rby = 0.f;
        if (s < SN - 1) {
            rfx = cx - coords[((size_t)(s + 1) * NN + n) * 2 + 0];
            rfy = cy - coords[((size_t)(s + 1) * NN + n) * 2 + 1];
        }
        if (s > 0) {
            rbx = cx - coords[((size_t)(s - 1) * NN + n) * 2 + 0];
            rby = cy - coords[((size_t)(s - 1) * NN + n) * 2 + 1];
        }
        float r4[4] = {rfx / 128.f, rfy / 96.f, rbx / 128.f, rby / 96.f};
        float val;
        if (rd < 4) {
            val = r4[rd];
        } else if (rd < 44) {
            int q = rd - 4; int deg = q >> 2, comp = q & 3;
            val = sinf(r4[comp] * (float)(1 << deg));
        } else {
            int q = rd - 44; int deg = q >> 2, comp = q & 3;
            val = sinf(r4[comp] * (float)(1 << deg) + 1.57079632679489662f);
        }
        int od = 1026 + rd;
        out[ob + od] = val + te[s * DOUT + od];
    }
}

extern "C" void kernel_launch(void* const* d_in, const int* in_sizes, int n_in,
                              void* d_out, int out_size, void* d_ws, size_t ws_size,
                              hipStream_t stream) {
    const float* fmaps[4] = {(const float*)d_in[0], (const float*)d_in[2],
                             (const float*)d_in[4], (const float*)d_in[6]};
    const float* track[4] = {(const float*)d_in[1], (const float*)d_in[3],
                             (const float*)d_in[5], (const float*)d_in[7]};
    const float* coords = (const float*)d_in[8];
    const float* vis    = (const float*)d_in[9];
    const float* conf   = (const float*)d_in[10];
    const float* w1     = (const float*)d_in[11];
    const float* b1     = (const float*)d_in[12];
    const float* w2     = (const float*)d_in[13];
    const float* b2     = (const float*)d_in[14];
    const float* te     = (const float*)d_in[15];
    float* out = (float*)d_out;

    const int Hs[4] = {96, 48, 24, 12};
    const int Ws[4] = {128, 64, 32, 16};

    // ---- workspace layout ----
    char* wsb = (char*)d_ws;
    unsigned short* w1t = (unsigned short*)wsb;
    size_t off = (size_t)H1 * K1P * 2;
    unsigned short* w2t = (unsigned short*)(wsb + off);
    off += (size_t)H2 * H1 * 2;
    unsigned short* fpad[4];
    for (int l = 0; l < 4; ++l) {
        fpad[l] = (unsigned short*)(wsb + off);
        off += (size_t)SN * (Hs[l] + 8) * (Ws[l] + 8) * CC * 2;
    }
    off += 512;  // slack for benign over-reads
    const size_t fixed = off;
    int s_chunk = SN;
    while (s_chunk > 1 &&
           fixed + (size_t)s_chunk * NN * (K1P + H1) * 2 > ws_size)
        s_chunk >>= 1;
    unsigned short* volb = (unsigned short*)(wsb + fixed);
    unsigned short* hb   = volb + (size_t)s_chunk * NN * K1P;

    // ---- weight prep + fmap conversion ----
    conv_t_kernel<<<dim3(K1P / 32, H1 / 32), 256, 0, stream>>>(w1, w1t, 2401, H1, K1P);
    conv_t_kernel<<<dim3(H1 / 32, H2 / 32), 256, 0, stream>>>(w2, w2t, H1, H2, H1);
    for (int l = 0; l < 4; ++l)
        conv_fmap_kernel<<<SN * (Hs[l] + 8), 256, 0, stream>>>(
            fmaps[l], fpad[l], Hs[l], Ws[l]);

    for (int lvl = 0; lvl < 4; ++lvl) {
        for (int s0 = 0; s0 < SN; s0 += s_chunk) {
            int rows = s_chunk * NN;
            sample_vol_kernel<<<NN, 256, 0, stream>>>(
                fpad[lvl], track[lvl], coords, volb,
                Hs[lvl] + 8, Ws[lvl] + 8, lvl, s0, s_chunk);
            gemm1_kernel<<<(rows / 128) * 3, 256, 0, stream>>>(volb, w1t, b1, hb);
            gemm2_kernel<<<(rows / 128) * 2, 256, 0, stream>>>(hb, w2t, b2, te, out, s0, lvl);
        }
    }
    tail_kernel<<<SN * NN, 128, 0, stream>>>(coords, vis, conf, te, out);
}

// Round 5
// 409.399 us; speedup vs baseline: 6.4221x; 1.4257x over previous
//
#include <hip/hip_runtime.h>
#include <math.h>

// ---------------------------------------------------------------------------
// CoTracker correlation-embedding pipeline, bf16 MFMA, HWC-padded fmaps.
// Round 4: level-fused MLP GEMMs (w1/w2 shared across levels) + counted-vmcnt
// double-buffer pipeline (no vmcnt(0) drain in the K-loop).
// Inputs: 0:fmaps0 1:track0 2:fmaps1 3:track1 4:fmaps2 5:track2 6:fmaps3
//         7:track3 8:coords 9:vis 10:conf 11:w1 12:b1 13:w2 14:b2 15:time_emb
// Output: (1,N,8,1110) f32.
// ---------------------------------------------------------------------------

#define SN 8
#define NN 1024
#define CC 128
#define K1P 2432
#define H1 384
#define H2 256
#define DOUT 1110

typedef short bf16x8 __attribute__((ext_vector_type(8)));
typedef float f32x4 __attribute__((ext_vector_type(4)));

__device__ inline unsigned short f2b(float x) {  // RTNE f32 -> bf16
    union { float f; unsigned u; } v; v.f = x;
    unsigned r = v.u + 0x7FFFu + ((v.u >> 16) & 1u);
    return (unsigned short)(r >> 16);
}
__device__ inline float b2f(unsigned short u) {
    union { unsigned u; float f; } v; v.u = (unsigned)u << 16; return v.f;
}
__device__ inline void gll16(const void* g, void* l) {
    __builtin_amdgcn_global_load_lds(
        (const __attribute__((address_space(1))) void*)g,
        (__attribute__((address_space(3))) void*)l, 16, 0, 0);
}
// XOR-swizzled LDS index (shorts) for [rows][128] bf16 MFMA operand tiles.
__device__ inline int swz(int row, int g) {
    return row * 128 + ((g ^ (row & 7)) << 3);
}

// ---------------------------------------------------------------------------
// fmap fp32 (S,C,H,W) -> bf16 HWC padded (S, H+8, W+8, C), border replicate.
// ---------------------------------------------------------------------------
__global__ __launch_bounds__(256) void conv_fmap_kernel(
    const float* __restrict__ in, unsigned short* __restrict__ outp,
    int H, int W)
{
    const int Hp = H + 8, Wp = W + 8;
    const int s = blockIdx.x / Hp, yp = blockIdx.x % Hp;
    const int y = min(max(yp - 4, 0), H - 1);
    const float* src = in + (size_t)s * CC * H * W + (size_t)y * W;
    unsigned short* dst = outp + ((size_t)s * Hp + yp) * Wp * CC;
    for (int idx = threadIdx.x; idx < Wp * CC; idx += 256) {
        int xp = idx >> 7, c = idx & 127;
        int x = min(max(xp - 4, 0), W - 1);
        dst[idx] = f2b(src[(size_t)c * H * W + x]);
    }
}

// ---------------------------------------------------------------------------
// Kernel A: per-n block. trk loaded once (swizzled). Per s:
//   patch (80 x 128 bf16, swizzled via pre-swizzled global src) staged by
//   global_load_lds (prefetched during prev bilinear) ->
//   MFMA pc[80][49] -> LDS -> bilinear on output domain -> vol row (packed).
// ---------------------------------------------------------------------------
__global__ __launch_bounds__(256, 2) void sample_vol_kernel(
    const unsigned short* __restrict__ fpad, // (8, Hp, Wp, 128) bf16
    const float* __restrict__ track,         // (49, N, 128) f32
    const float* __restrict__ coords,        // (8, N, 2) f32
    unsigned short* __restrict__ vol,        // (8*N, 2432) bf16
    int Hp, int Wp, int lvl)
{
    __shared__ __align__(16) unsigned short patch[80 * 128];  // 20.0 KB
    __shared__ __align__(16) unsigned short trk[64 * 128];    // 16 KB
    __shared__ __align__(16) float pcL[80 * 68];              // 21.75 KB
    const int n = blockIdx.x, t = threadIdx.x;
    const int lane = t & 63, wv = t >> 6;
    const int rsub = lane & 15, kq = lane >> 4;
    const float inv = 1.0f / (float)(1 << lvl);
    const size_t plane = (size_t)Hp * Wp * CC;

    int poff[5], ldso[5];
    #pragma unroll
    for (int i = 0; i < 5; ++i) {
        int task64 = wv * 5 + i;
        int point = task64 * 4 + (lane >> 4);  // patch row 0..79
        int v = point / 10, xs = point - v * 10;
        int j = (lane & 15) ^ (point & 7);     // logical granule to fetch
        poff[i] = (v * Wp + xs) * CC + j * 8;
        ldso[i] = task64 * 512;
    }

    float cx = coords[((size_t)0 * NN + n) * 2 + 0] * inv;
    float cy = coords[((size_t)0 * NN + n) * 2 + 1] * inv;
    int fx = (int)floorf(cx), fy = (int)floorf(cy);
    int e = (fx - 3) & ~1;
    {
        const unsigned short* base =
            fpad + ((fy + 1) * Wp + (e + 4)) * CC;
        #pragma unroll
        for (int i = 0; i < 5; ++i) gll16(base + poff[i], &patch[ldso[i]]);
    }
    for (int task = t; task < 49 * 16; task += 256) {
        int row = task >> 4, g = task & 15;
        const float* srcp = &track[((size_t)row * NN + n) * CC + g * 8];
        float4 f0 = *(const float4*)srcp;
        float4 f1 = *(const float4*)(srcp + 4);
        bf16x8 v8;
        v8[0] = f2b(f0.x); v8[1] = f2b(f0.y); v8[2] = f2b(f0.z); v8[3] = f2b(f0.w);
        v8[4] = f2b(f1.x); v8[5] = f2b(f1.y); v8[6] = f2b(f1.z); v8[7] = f2b(f1.w);
        *(bf16x8*)&trk[swz(row, g)] = v8;
    }

    for (int sl = 0; sl < SN; ++sl) {
        const float wx = cx - (float)fx, wy = cy - (float)fy;
        const float w00 = (1.f - wx) * (1.f - wy), w10 = wx * (1.f - wy);
        const float w01 = (1.f - wx) * wy,         w11 = wx * wy;
        const int off = fx - 3 - e;

        asm volatile("s_waitcnt vmcnt(0)" ::: "memory");
        __syncthreads();   // patch landed; prev bilinear readers of pcL done

        // ---- MFMA: pc[80][64] = patch(80x128) . trk(64x128)^T ----
        {
            f32x4 acc[5] = {};
            #pragma unroll
            for (int kk = 0; kk < 4; ++kk) {
                int gg = kk * 4 + kq;
                bf16x8 b = *(const bf16x8*)&trk[swz(wv * 16 + rsub, gg)];
                #pragma unroll
                for (int ti = 0; ti < 5; ++ti) {
                    int row = ti * 16 + rsub;
                    bf16x8 a = *(const bf16x8*)&patch[swz(row, gg)];
                    acc[ti] = __builtin_amdgcn_mfma_f32_16x16x32_bf16(a, b, acc[ti], 0, 0, 0);
                }
            }
            #pragma unroll
            for (int ti = 0; ti < 5; ++ti)
                #pragma unroll
                for (int r = 0; r < 4; ++r)
                    pcL[(ti * 16 + kq * 4 + r) * 68 + wv * 16 + rsub] = acc[ti][r];
        }
        __syncthreads();   // pc ready; patch consumed

        // ---- issue next-s patch loads (overlap with bilinear) ----
        if (sl + 1 < SN) {
            int s2 = sl + 1;
            cx = coords[((size_t)s2 * NN + n) * 2 + 0] * inv;
            cy = coords[((size_t)s2 * NN + n) * 2 + 1] * inv;
            fx = (int)floorf(cx); fy = (int)floorf(cy);
            e = (fx - 3) & ~1;
            const unsigned short* base =
                fpad + (size_t)s2 * plane + ((fy + 1) * Wp + (e + 4)) * CC;
            #pragma unroll
            for (int i = 0; i < 5; ++i) gll16(base + poff[i], &patch[ldso[i]]);
        }

        // ---- bilinear on output domain; packed b32 coalesced stores ----
        {
            unsigned* vrow32 = (unsigned*)(vol + ((size_t)sl * NN + n) * K1P);
            for (int d = t; d < K1P / 2; d += 256) {
                int s0 = 2 * d;
                unsigned pk = 0;
                if (s0 < 2401) {
                    int ab0 = s0 / 49, ij0 = s0 - 49 * ab0;
                    int a0 = ab0 / 7, b0 = ab0 - 7 * a0;
                    int p0 = b0 * 10 + off + a0;
                    const float* q = &pcL[p0 * 68 + ij0];
                    float v0 = w00 * q[0] + w10 * q[68] + w01 * q[680] + w11 * q[748];
                    unsigned short lo = f2b(v0), hi = 0;
                    int s1 = s0 + 1;
                    if (s1 < 2401) {
                        int ab1 = ab0, ij1 = ij0 + 1;
                        if (ij1 == 49) { ij1 = 0; ab1 = ab0 + 1; }
                        int a1 = ab1 / 7, b1 = ab1 - 7 * a1;
                        int p1 = b1 * 10 + off + a1;
                        const float* q1 = &pcL[p1 * 68 + ij1];
                        float v1 = w00 * q1[0] + w10 * q1[68] + w01 * q1[680] + w11 * q1[748];
                        hi = f2b(v1);
                    }
                    pk = (unsigned)lo | ((unsigned)hi << 16);
                }
                vrow32[d] = pk;
            }
        }
    }
}

// ---------------------------------------------------------------------------
// GEMM1: H = gelu(vol @ w1 + b1).  (rows x 2432) @ (2432 x 384) bf16.
// Counted-vmcnt double-buffer: prologue stages 2 tiles; per iter
// vmcnt(4) -> barrier -> ds_read+MFMA -> barrier -> restage for st+2.
// ---------------------------------------------------------------------------
__global__ __launch_bounds__(256) void gemm1_kernel(
    const unsigned short* __restrict__ A,   // rows x 2432
    const unsigned short* __restrict__ Bt,  // 384 x 2432 (= w1^T)
    const float* __restrict__ bias,
    unsigned short* __restrict__ Hout)      // rows x 384
{
    __shared__ __align__(16) unsigned short As[2][128 * 32];
    __shared__ __align__(16) unsigned short Bs[2][128 * 32];
    const int h = blockIdx.x, q = gridDim.x >> 3;
    const int l = (h & 7) * q + (h >> 3);
    const int m0 = (l / 3) * 128, n0 = (l % 3) * 128;
    const int t = threadIdx.x, lane = t & 63, wv = t >> 6;
    const int wm = wv >> 1, wn = wv & 1;
    const int rsub = lane & 15, kq = lane >> 4;

    const int rA0 = t >> 2, sA0 = (t & 3) ^ ((rA0 >> 1) & 3);
    const int rA1 = (t + 256) >> 2, sA1 = ((t + 256) & 3) ^ ((rA1 >> 1) & 3);
    const unsigned short* gA0 = A  + (size_t)(m0 + rA0) * K1P + sA0 * 8;
    const unsigned short* gA1 = A  + (size_t)(m0 + rA1) * K1P + sA1 * 8;
    const unsigned short* gB0 = Bt + (size_t)(n0 + rA0) * K1P + sA0 * 8;
    const unsigned short* gB1 = Bt + (size_t)(n0 + rA1) * K1P + sA1 * 8;
    const int chunk0 = (t & ~63) * 8, chunk1 = (256 + (t & ~63)) * 8;

    f32x4 acc[4][4] = {};

    const int NSTEP = K1P / 32;  // 76
    {
        gll16(gA0, &As[0][chunk0]); gll16(gA1, &As[0][chunk1]);
        gll16(gB0, &Bs[0][chunk0]); gll16(gB1, &Bs[0][chunk1]);
        gll16(gA0 + 32, &As[1][chunk0]); gll16(gA1 + 32, &As[1][chunk1]);
        gll16(gB0 + 32, &Bs[1][chunk0]); gll16(gB1 + 32, &Bs[1][chunk1]);
    }
    for (int st = 0; st < NSTEP; ++st) {
        const int cur = st & 1;
        asm volatile("s_waitcnt vmcnt(4)" ::: "memory");
        __builtin_amdgcn_s_barrier();
        __builtin_amdgcn_sched_barrier(0);
        bf16x8 af[4], bfr[4];
        #pragma unroll
        for (int mi = 0; mi < 4; ++mi) {
            int r = wm * 64 + mi * 16 + rsub;
            int phys = r * 4 + (kq ^ ((r >> 1) & 3));
            af[mi] = *(const bf16x8*)&As[cur][phys * 8];
        }
        #pragma unroll
        for (int ni = 0; ni < 4; ++ni) {
            int r = wn * 64 + ni * 16 + rsub;
            int phys = r * 4 + (kq ^ ((r >> 1) & 3));
            bfr[ni] = *(const bf16x8*)&Bs[cur][phys * 8];
        }
        #pragma unroll
        for (int mi = 0; mi < 4; ++mi)
            #pragma unroll
            for (int ni = 0; ni < 4; ++ni)
                acc[mi][ni] = __builtin_amdgcn_mfma_f32_16x16x32_bf16(
                    af[mi], bfr[ni], acc[mi][ni], 0, 0, 0);
        __builtin_amdgcn_sched_barrier(0);
        __builtin_amdgcn_s_barrier();
        __builtin_amdgcn_sched_barrier(0);
        if (st + 2 < NSTEP) {
            size_t ko = (size_t)(st + 2) * 32;
            gll16(gA0 + ko, &As[cur][chunk0]);
            gll16(gA1 + ko, &As[cur][chunk1]);
            gll16(gB0 + ko, &Bs[cur][chunk0]);
            gll16(gB1 + ko, &Bs[cur][chunk1]);
        }
    }
    #pragma unroll
    for (int mi = 0; mi < 4; ++mi) {
        int row = m0 + wm * 64 + mi * 16 + kq * 4;
        #pragma unroll
        for (int ni = 0; ni < 4; ++ni) {
            int col = n0 + wn * 64 + ni * 16 + rsub;
            float bcol = bias[col];
            #pragma unroll
            for (int r = 0; r < 4; ++r) {
                float x = acc[mi][ni][r] + bcol;
                float g = 0.5f * x * (1.f + erff(x * 0.70710678118654752f));
                Hout[(size_t)(row + r) * H1 + col] = f2b(g);
            }
        }
    }
}

// ---------------------------------------------------------------------------
// GEMM2: out slice = H @ w2 + b2 + time_emb.  (rows x 384) @ (384 x 256).
// Rows span n_lv fused levels: row -> (g=row>>13, s=(row>>10)&7, n=row&1023).
// ---------------------------------------------------------------------------
__global__ __launch_bounds__(256) void gemm2_kernel(
    const unsigned short* __restrict__ A,   // rows x 384
    const unsigned short* __restrict__ Bt,  // 256 x 384 (= w2^T)
    const float* __restrict__ bias,
    const float* __restrict__ te,           // (8, 1110)
    float* __restrict__ out,                // (N, 8, 1110)
    int lv0)
{
    __shared__ __align__(16) unsigned short As[2][128 * 32];
    __shared__ __align__(16) unsigned short Bs[2][128 * 32];
    const int h = blockIdx.x, q = gridDim.x >> 3;
    const int l = (h & 7) * q + (h >> 3);
    const int m0 = (l >> 1) * 128, n0 = (l & 1) * 128;
    const int t = threadIdx.x, lane = t & 63, wv = t >> 6;
    const int wm = wv >> 1, wn = wv & 1;
    const int rsub = lane & 15, kq = lane >> 4;

    const int rA0 = t >> 2, sA0 = (t & 3) ^ ((rA0 >> 1) & 3);
    const int rA1 = (t + 256) >> 2, sA1 = ((t + 256) & 3) ^ ((rA1 >> 1) & 3);
    const unsigned short* gA0 = A  + (size_t)(m0 + rA0) * H1 + sA0 * 8;
    const unsigned short* gA1 = A  + (size_t)(m0 + rA1) * H1 + sA1 * 8;
    const unsigned short* gB0 = Bt + (size_t)(n0 + rA0) * H1 + sA0 * 8;
    const unsigned short* gB1 = Bt + (size_t)(n0 + rA1) * H1 + sA1 * 8;
    const int chunk0 = (t & ~63) * 8, chunk1 = (256 + (t & ~63)) * 8;

    f32x4 acc[4][4] = {};

    const int NSTEP = H1 / 32;  // 12
    {
        gll16(gA0, &As[0][chunk0]); gll16(gA1, &As[0][chunk1]);
        gll16(gB0, &Bs[0][chunk0]); gll16(gB1, &Bs[0][chunk1]);
        gll16(gA0 + 32, &As[1][chunk0]); gll16(gA1 + 32, &As[1][chunk1]);
        gll16(gB0 + 32, &Bs[1][chunk0]); gll16(gB1 + 32, &Bs[1][chunk1]);
    }
    for (int st = 0; st < NSTEP; ++st) {
        const int cur = st & 1;
        asm volatile("s_waitcnt vmcnt(4)" ::: "memory");
        __builtin_amdgcn_s_barrier();
        __builtin_amdgcn_sched_barrier(0);
        bf16x8 af[4], bfr[4];
        #pragma unroll
        for (int mi = 0; mi < 4; ++mi) {
            int r = wm * 64 + mi * 16 + rsub;
            int phys = r * 4 + (kq ^ ((r >> 1) & 3));
            af[mi] = *(const bf16x8*)&As[cur][phys * 8];
        }
        #pragma unroll
        for (int ni = 0; ni < 4; ++ni) {
            int r = wn * 64 + ni * 16 + rsub;
            int phys = r * 4 + (kq ^ ((r >> 1) & 3));
            bfr[ni] = *(const bf16x8*)&Bs[cur][phys * 8];
        }
        #pragma unroll
        for (int mi = 0; mi < 4; ++mi)
            #pragma unroll
            for (int ni = 0; ni < 4; ++ni)
                acc[mi][ni] = __builtin_amdgcn_mfma_f32_16x16x32_bf16(
                    af[mi], bfr[ni], acc[mi][ni], 0, 0, 0);
        __builtin_amdgcn_sched_barrier(0);
        __builtin_amdgcn_s_barrier();
        __builtin_amdgcn_sched_barrier(0);
        if (st + 2 < NSTEP) {
            size_t ko = (size_t)(st + 2) * 32;
            gll16(gA0 + ko, &As[cur][chunk0]);
            gll16(gA1 + ko, &As[cur][chunk1]);
            gll16(gB0 + ko, &Bs[cur][chunk0]);
            gll16(gB1 + ko, &Bs[cur][chunk1]);
        }
    }
    #pragma unroll
    for (int mi = 0; mi < 4; ++mi) {
        int rowb = m0 + wm * 64 + mi * 16 + kq * 4;
        #pragma unroll
        for (int ni = 0; ni < 4; ++ni) {
            int col = n0 + wn * 64 + ni * 16 + rsub;
            float bcol = bias[col];
            #pragma unroll
            for (int r = 0; r < 4; ++r) {
                int row = rowb + r;
                int g = row >> 13, s = (row >> 10) & 7, n = row & 1023;
                int dcol = 2 + (lv0 + g) * H2 + col;
                out[((size_t)n * SN + s) * DOUT + dcol] =
                    acc[mi][ni][r] + bcol + te[s * DOUT + dcol];
            }
        }
    }
}

// ---------------------------------------------------------------------------
// Transpose + bf16-convert: in (K x Nw f32) -> out (Nw x Kp bf16), zero-pad.
// ---------------------------------------------------------------------------
__global__ __launch_bounds__(256) void conv_t_kernel(
    const float* __restrict__ in, unsigned short* __restrict__ outp,
    int K, int Nw, int Kp)
{
    __shared__ float tile[32][33];
    const int kb = blockIdx.x * 32, nb = blockIdx.y * 32;
    const int tx = threadIdx.x & 31, ty = threadIdx.x >> 5;
    #pragma unroll
    for (int i = 0; i < 32; i += 8) {
        int k = kb + ty + i, nn = nb + tx;
        tile[ty + i][tx] = (k < K && nn < Nw) ? in[(size_t)k * Nw + nn] : 0.f;
    }
    __syncthreads();
    #pragma unroll
    for (int i = 0; i < 32; i += 8) {
        int nn = nb + ty + i, k = kb + tx;
        if (nn < Nw) outp[(size_t)nn * Kp + k] = f2b(tile[tx][ty + i]);
    }
}

// Kernel D: vis, conf, rel_emb(84) + time_emb.
__global__ __launch_bounds__(128) void tail_kernel(
    const float* __restrict__ coords, const float* __restrict__ vis,
    const float* __restrict__ conf, const float* __restrict__ te,
    float* __restrict__ out)
{
    const int b = blockIdx.x;
    const int n = b >> 3, s = b & 7;
    const int d = threadIdx.x;
    if (d >= 86) return;
    const size_t ob = (size_t)b * DOUT;
    if (d == 0) {
        out[ob + 0] = vis[(size_t)s * NN + n] + te[s * DOUT + 0];
    } else if (d == 1) {
        out[ob + 1] = conf[(size_t)s * NN + n] + te[s * DOUT + 1];
    } else {
        int rd = d - 2;
        float cx = coords[((size_t)s * NN + n) * 2 + 0];
        float cy = coords[((size_t)s * NN + n) * 2 + 1];
        float rfx = 0.f, rfy = 0.f, rbx = 0.f, rby = 0.f;
        if (s < SN - 1) {
            rfx = cx - coords[((size_t)(s + 1) * NN + n) * 2 + 0];
            rfy = cy - coords[((size_t)(s + 1) * NN + n) * 2 + 1];
        }
        if (s > 0) {
            rbx = cx - coords[((size_t)(s - 1) * NN + n) * 2 + 0];
            rby = cy - coords[((size_t)(s - 1) * NN + n) * 2 + 1];
        }
        float r4[4] = {rfx / 128.f, rfy / 96.f, rbx / 128.f, rby / 96.f};
        float val;
        if (rd < 4) {
            val = r4[rd];
        } else if (rd < 44) {
            int q = rd - 4; int deg = q >> 2, comp = q & 3;
            val = sinf(r4[comp] * (float)(1 << deg));
        } else {
            int q = rd - 44; int deg = q >> 2, comp = q & 3;
            val = sinf(r4[comp] * (float)(1 << deg) + 1.57079632679489662f);
        }
        int od = 1026 + rd;
        out[ob + od] = val + te[s * DOUT + od];
    }
}

extern "C" void kernel_launch(void* const* d_in, const int* in_sizes, int n_in,
                              void* d_out, int out_size, void* d_ws, size_t ws_size,
                              hipStream_t stream) {
    const float* fmaps[4] = {(const float*)d_in[0], (const float*)d_in[2],
                             (const float*)d_in[4], (const float*)d_in[6]};
    const float* track[4] = {(const float*)d_in[1], (const float*)d_in[3],
                             (const float*)d_in[5], (const float*)d_in[7]};
    const float* coords = (const float*)d_in[8];
    const float* vis    = (const float*)d_in[9];
    const float* conf   = (const float*)d_in[10];
    const float* w1     = (const float*)d_in[11];
    const float* b1     = (const float*)d_in[12];
    const float* w2     = (const float*)d_in[13];
    const float* b2     = (const float*)d_in[14];
    const float* te     = (const float*)d_in[15];
    float* out = (float*)d_out;

    const int Hs[4] = {96, 48, 24, 12};
    const int Ws[4] = {128, 64, 32, 16};

    // ---- workspace layout ----
    char* wsb = (char*)d_ws;
    unsigned short* w1t = (unsigned short*)wsb;
    size_t off = (size_t)H1 * K1P * 2;
    unsigned short* w2t = (unsigned short*)(wsb + off);
    off += (size_t)H2 * H1 * 2;
    unsigned short* fpad[4];
    for (int l = 0; l < 4; ++l) {
        fpad[l] = (unsigned short*)(wsb + off);
        off += (size_t)SN * (Hs[l] + 8) * (Ws[l] + 8) * CC * 2;
    }
    off += 512;  // slack for benign over-reads
    const size_t fixed = off;
    // levels fused per group: vol(n_lv*8192*2432) + h(n_lv*8192*384), bf16
    int n_lv = 4;
    while (n_lv > 1 &&
           fixed + (size_t)n_lv * SN * NN * (K1P + H1) * 2 > ws_size)
        n_lv >>= 1;
    unsigned short* volb = (unsigned short*)(wsb + fixed);
    unsigned short* hb   = volb + (size_t)n_lv * SN * NN * K1P;

    // ---- weight prep + fmap conversion ----
    conv_t_kernel<<<dim3(K1P / 32, H1 / 32), 256, 0, stream>>>(w1, w1t, 2401, H1, K1P);
    conv_t_kernel<<<dim3(H1 / 32, H2 / 32), 256, 0, stream>>>(w2, w2t, H1, H2, H1);
    for (int l = 0; l < 4; ++l)
        conv_fmap_kernel<<<SN * (Hs[l] + 8), 256, 0, stream>>>(
            fmaps[l], fpad[l], Hs[l], Ws[l]);

    for (int lv0 = 0; lv0 < 4; lv0 += n_lv) {
        for (int g = 0; g < n_lv; ++g) {
            int l = lv0 + g;
            sample_vol_kernel<<<NN, 256, 0, stream>>>(
                fpad[l], track[l], coords, volb + (size_t)g * SN * NN * K1P,
                Hs[l] + 8, Ws[l] + 8, l);
        }
        const int rows = n_lv * SN * NN;
        gemm1_kernel<<<(rows / 128) * 3, 256, 0, stream>>>(volb, w1t, b1, hb);
        gemm2_kernel<<<(rows / 128) * 2, 256, 0, stream>>>(hb, w2t, b2, te, out, lv0);
    }
    tail_kernel<<<SN * NN, 128, 0, stream>>>(coords, vis, conf, te, out);
}

// Round 6
// 347.524 us; speedup vs baseline: 7.5655x; 1.1780x over previous
//
#include <hip/hip_runtime.h>
#include <math.h>

// ---------------------------------------------------------------------------
// CoTracker correlation-embedding pipeline, bf16 MFMA, HWC-padded fmaps.
// Round 5: fused 4-level sample_vol (3 blocks/CU, bf16 pc, register LUT,
// hoisted coords) + 3-buffer counted-vmcnt GEMM pipeline.
// Inputs: 0:fmaps0 1:track0 2:fmaps1 3:track1 4:fmaps2 5:track2 6:fmaps3
//         7:track3 8:coords 9:vis 10:conf 11:w1 12:b1 13:w2 14:b2 15:time_emb
// Output: (1,N,8,1110) f32.
// ---------------------------------------------------------------------------

#define SN 8
#define NN 1024
#define CC 128
#define K1P 2432
#define H1 384
#define H2 256
#define DOUT 1110

typedef short bf16x8 __attribute__((ext_vector_type(8)));
typedef float f32x4 __attribute__((ext_vector_type(4)));

__device__ inline unsigned short f2b(float x) {  // RTNE f32 -> bf16
    union { float f; unsigned u; } v; v.f = x;
    unsigned r = v.u + 0x7FFFu + ((v.u >> 16) & 1u);
    return (unsigned short)(r >> 16);
}
__device__ inline float b2f(unsigned short u) {
    union { unsigned u; float f; } v; v.u = (unsigned)u << 16; return v.f;
}
__device__ inline void gll16(const void* g, void* l) {
    __builtin_amdgcn_global_load_lds(
        (const __attribute__((address_space(1))) void*)g,
        (__attribute__((address_space(3))) void*)l, 16, 0, 0);
}
// XOR-swizzled LDS index (shorts) for [rows][128] bf16 MFMA operand tiles.
__device__ inline int swz(int row, int g) {
    return row * 128 + ((g ^ (row & 7)) << 3);
}

// ---------------------------------------------------------------------------
// fmap fp32 (S,C,H,W) -> bf16 HWC padded (S, H+8, W+8, C), border replicate.
// ---------------------------------------------------------------------------
__global__ __launch_bounds__(256) void conv_fmap_kernel(
    const float* __restrict__ in, unsigned short* __restrict__ outp,
    int H, int W)
{
    const int Hp = H + 8, Wp = W + 8;
    const int s = blockIdx.x / Hp, yp = blockIdx.x % Hp;
    const int y = min(max(yp - 4, 0), H - 1);
    const float* src = in + (size_t)s * CC * H * W + (size_t)y * W;
    unsigned short* dst = outp + ((size_t)s * Hp + yp) * Wp * CC;
    for (int idx = threadIdx.x; idx < Wp * CC; idx += 256) {
        int xp = idx >> 7, c = idx & 127;
        int x = min(max(xp - 4, 0), W - 1);
        dst[idx] = f2b(src[(size_t)c * H * W + x]);
    }
}

// ---------------------------------------------------------------------------
// Kernel A (fused over levels): block -> (g = blk>>10, n = blk&1023).
// trk loaded once (swizzled). Per s (fully unrolled):
//   patch (80x128 bf16, pre-swizzled global src) via global_load_lds
//   (prefetched during prev bilinear) -> MFMA pc[80][64] -> pcL bf16 [80][66]
//   -> bilinear on output domain (register LUT, u16 taps) -> vol row packed.
// LDS ~44.9KB -> 3 blocks/CU.
// ---------------------------------------------------------------------------
__global__ __launch_bounds__(256, 3) void sample_vol_kernel(
    const unsigned short* __restrict__ fq0, const unsigned short* __restrict__ fq1,
    const unsigned short* __restrict__ fq2, const unsigned short* __restrict__ fq3,
    const float* __restrict__ tk0, const float* __restrict__ tk1,
    const float* __restrict__ tk2, const float* __restrict__ tk3,
    const float* __restrict__ coords,        // (8, N, 2) f32
    unsigned short* __restrict__ vol,        // (n_lv*8*N, 2432) bf16
    int lv0)
{
    __shared__ __align__(16) unsigned short patch[80 * 128]; // 20 KB
    __shared__ __align__(16) unsigned short trk[64 * 128];   // 16 KB
    __shared__ __align__(16) unsigned short pcL[80 * 66];    // 10.3 KB
    const int n = blockIdx.x & 1023, g = blockIdx.x >> 10;
    const int lvl = lv0 + g;
    const unsigned short* fpad = (lvl == 0) ? fq0 : (lvl == 1) ? fq1
                               : (lvl == 2) ? fq2 : fq3;
    const float* track = (lvl == 0) ? tk0 : (lvl == 1) ? tk1
                       : (lvl == 2) ? tk2 : tk3;
    const int Wp = (128 >> lvl) + 8;
    const int t = threadIdx.x;
    const int lane = t & 63, wv = t >> 6;
    const int rsub = lane & 15, kq = lane >> 4;
    const float inv = 1.0f / (float)(1 << lvl);
    const size_t plane = (size_t)((96 >> lvl) + 8) * Wp * CC;

    // per-lane static patch-load offsets (pre-swizzled global granule)
    int poff[5], ldso[5];
    #pragma unroll
    for (int i = 0; i < 5; ++i) {
        int task64 = wv * 5 + i;
        int point = task64 * 4 + (lane >> 4);  // patch row 0..79
        int v = point / 10, xs = point - v * 10;
        int j = (lane & 15) ^ (point & 7);
        poff[i] = (v * Wp + xs) * CC + j * 8;
        ldso[i] = task64 * 512;
    }

    // hoist all 8 coords into registers
    float cxa[SN], cya[SN];
    #pragma unroll
    for (int s = 0; s < SN; ++s) {
        float2 c2 = *(const float2*)&coords[((size_t)s * NN + n) * 2];
        cxa[s] = c2.x * inv; cya[s] = c2.y * inv;
    }

    // register LUT for bilinear output decomposition (divs once per thread)
    unsigned lutA[5], lutB[5];
    #pragma unroll
    for (int i = 0; i < 5; ++i) {
        int d = t + i * 256;
        int o0 = 2 * d, o1 = 2 * d + 1;
        lutA[i] = 0xFFFFFFFFu; lutB[i] = 0xFFFFFFFFu;
        if (o0 < 2401) {
            int ab = o0 / 49, ij = o0 - 49 * ab, a = ab / 7, b = ab - 7 * a;
            lutA[i] = (unsigned)((b * 10 + a) * 66 + ij);
        }
        if (o1 < 2401) {
            int ab = o1 / 49, ij = o1 - 49 * ab, a = ab / 7, b = ab - 7 * a;
            lutB[i] = (unsigned)((b * 10 + a) * 66 + ij);
        }
    }

    // first patch issue
    int fx = (int)floorf(cxa[0]), fy = (int)floorf(cya[0]);
    int e = (fx - 3) & ~1;
    {
        const unsigned short* base = fpad + ((fy + 1) * Wp + (e + 4)) * CC;
        #pragma unroll
        for (int i = 0; i < 5; ++i) gll16(base + poff[i], &patch[ldso[i]]);
    }
    // track[n] -> trk LDS (swizzled), once
    for (int task = t; task < 49 * 16; task += 256) {
        int row = task >> 4, gg = task & 15;
        const float* srcp = &track[((size_t)row * NN + n) * CC + gg * 8];
        float4 f0 = *(const float4*)srcp;
        float4 f1 = *(const float4*)(srcp + 4);
        bf16x8 v8;
        v8[0] = f2b(f0.x); v8[1] = f2b(f0.y); v8[2] = f2b(f0.z); v8[3] = f2b(f0.w);
        v8[4] = f2b(f1.x); v8[5] = f2b(f1.y); v8[6] = f2b(f1.z); v8[7] = f2b(f1.w);
        *(bf16x8*)&trk[swz(row, gg)] = v8;
    }

    #pragma unroll
    for (int sl = 0; sl < SN; ++sl) {
        const float wx = cxa[sl] - (float)fx, wy = cya[sl] - (float)fy;
        const float w00 = (1.f - wx) * (1.f - wy), w10 = wx * (1.f - wy);
        const float w01 = (1.f - wx) * wy,         w11 = wx * wy;
        const int offs = (fx - 3 - e) * 66;

        asm volatile("s_waitcnt vmcnt(0)" ::: "memory");
        __syncthreads();   // patch landed; prev bilinear readers of pcL done

        // ---- MFMA: pc[80][64] = patch(80x128) . trk(64x128)^T -> pcL bf16 --
        {
            f32x4 acc[5] = {};
            #pragma unroll
            for (int kk = 0; kk < 4; ++kk) {
                int gg = kk * 4 + kq;
                bf16x8 b = *(const bf16x8*)&trk[swz(wv * 16 + rsub, gg)];
                #pragma unroll
                for (int ti = 0; ti < 5; ++ti) {
                    bf16x8 a = *(const bf16x8*)&patch[swz(ti * 16 + rsub, gg)];
                    acc[ti] = __builtin_amdgcn_mfma_f32_16x16x32_bf16(a, b, acc[ti], 0, 0, 0);
                }
            }
            const int col = wv * 16 + rsub;   // ij dim, 0..63 (<66 stride: safe)
            #pragma unroll
            for (int ti = 0; ti < 5; ++ti)
                #pragma unroll
                for (int r = 0; r < 4; ++r)
                    pcL[(ti * 16 + kq * 4 + r) * 66 + col] = f2b(acc[ti][r]);
        }
        __syncthreads();   // pcL ready; patch consumed

        // ---- issue next-s patch loads (overlap with bilinear) ----
        if (sl + 1 < SN) {
            fx = (int)floorf(cxa[sl + 1]); fy = (int)floorf(cya[sl + 1]);
            e = (fx - 3) & ~1;
            const unsigned short* base =
                fpad + (size_t)(sl + 1) * plane + ((fy + 1) * Wp + (e + 4)) * CC;
            #pragma unroll
            for (int i = 0; i < 5; ++i) gll16(base + poff[i], &patch[ldso[i]]);
        }

        // ---- bilinear on output domain; packed b32 coalesced stores ----
        {
            unsigned* vrow32 = (unsigned*)(vol + ((size_t)(g * SN + sl) * NN + n) * K1P);
            #pragma unroll
            for (int i = 0; i < 5; ++i) {
                int d = t + i * 256;
                if (d < K1P / 2) {
                    unsigned lo = 0, hi = 0;
                    if (lutA[i] != 0xFFFFFFFFu) {
                        int idx = (int)lutA[i] + offs;
                        float v = w00 * b2f(pcL[idx])       + w10 * b2f(pcL[idx + 66])
                                + w01 * b2f(pcL[idx + 660]) + w11 * b2f(pcL[idx + 726]);
                        lo = f2b(v);
                    }
                    if (lutB[i] != 0xFFFFFFFFu) {
                        int idx = (int)lutB[i] + offs;
                        float v = w00 * b2f(pcL[idx])       + w10 * b2f(pcL[idx + 66])
                                + w01 * b2f(pcL[idx + 660]) + w11 * b2f(pcL[idx + 726]);
                        hi = f2b(v);
                    }
                    vrow32[d] = lo | (hi << 16);
                }
            }
        }
    }
}

// ---------------------------------------------------------------------------
// GEMM1: H = gelu(vol @ w1 + b1).  (rows x 2432) @ (2432 x 384) bf16.
// 3-buffer counted-vmcnt pipeline: prologue stages 3 tiles; per iter
// vmcnt(8|4|0) -> barrier -> ds_read+MFMA -> barrier -> restage st+3.
// ---------------------------------------------------------------------------
__global__ __launch_bounds__(256, 3) void gemm1_kernel(
    const unsigned short* __restrict__ A,   // rows x 2432
    const unsigned short* __restrict__ Bt,  // 384 x 2432 (= w1^T)
    const float* __restrict__ bias,
    unsigned short* __restrict__ Hout)      // rows x 384
{
    __shared__ __align__(16) unsigned short As[3 * 128 * 32];
    __shared__ __align__(16) unsigned short Bs[3 * 128 * 32];
    const int h = blockIdx.x, q = gridDim.x >> 3;
    const int l = (h & 7) * q + (h >> 3);
    const int m0 = (l / 3) * 128, n0 = (l % 3) * 128;
    const int t = threadIdx.x, lane = t & 63, wv = t >> 6;
    const int wm = wv >> 1, wn = wv & 1;
    const int rsub = lane & 15, kq = lane >> 4;

    const int rA0 = t >> 2, sA0 = (t & 3) ^ ((rA0 >> 1) & 3);
    const int rA1 = (t + 256) >> 2, sA1 = ((t + 256) & 3) ^ ((rA1 >> 1) & 3);
    const unsigned short* gA0 = A  + (size_t)(m0 + rA0) * K1P + sA0 * 8;
    const unsigned short* gA1 = A  + (size_t)(m0 + rA1) * K1P + sA1 * 8;
    const unsigned short* gB0 = Bt + (size_t)(n0 + rA0) * K1P + sA0 * 8;
    const unsigned short* gB1 = Bt + (size_t)(n0 + rA1) * K1P + sA1 * 8;
    const int chunk0 = (t & ~63) * 8, chunk1 = (256 + (t & ~63)) * 8;

    f32x4 acc[4][4] = {};

    const int NSTEP = K1P / 32;  // 76
    #pragma unroll
    for (int p = 0; p < 3; ++p) {
        size_t ko = (size_t)p * 32;
        int lb = p * 4096;
        gll16(gA0 + ko, &As[lb + chunk0]); gll16(gA1 + ko, &As[lb + chunk1]);
        gll16(gB0 + ko, &Bs[lb + chunk0]); gll16(gB1 + ko, &Bs[lb + chunk1]);
    }
    int cur = 0;
    for (int st = 0; st < NSTEP; ++st) {
        const int rem = NSTEP - 1 - st;
        if (rem >= 2)      asm volatile("s_waitcnt vmcnt(8)" ::: "memory");
        else if (rem == 1) asm volatile("s_waitcnt vmcnt(4)" ::: "memory");
        else               asm volatile("s_waitcnt vmcnt(0)" ::: "memory");
        __builtin_amdgcn_s_barrier();
        __builtin_amdgcn_sched_barrier(0);
        const int lb = cur * 4096;
        bf16x8 af[4], bfr[4];
        #pragma unroll
        for (int mi = 0; mi < 4; ++mi) {
            int r = wm * 64 + mi * 16 + rsub;
            int phys = r * 4 + (kq ^ ((r >> 1) & 3));
            af[mi] = *(const bf16x8*)&As[lb + phys * 8];
        }
        #pragma unroll
        for (int ni = 0; ni < 4; ++ni) {
            int r = wn * 64 + ni * 16 + rsub;
            int phys = r * 4 + (kq ^ ((r >> 1) & 3));
            bfr[ni] = *(const bf16x8*)&Bs[lb + phys * 8];
        }
        #pragma unroll
        for (int mi = 0; mi < 4; ++mi)
            #pragma unroll
            for (int ni = 0; ni < 4; ++ni)
                acc[mi][ni] = __builtin_amdgcn_mfma_f32_16x16x32_bf16(
                    af[mi], bfr[ni], acc[mi][ni], 0, 0, 0);
        __builtin_amdgcn_sched_barrier(0);
        __builtin_amdgcn_s_barrier();
        __builtin_amdgcn_sched_barrier(0);
        if (st + 3 < NSTEP) {
            size_t ko = (size_t)(st + 3) * 32;
            gll16(gA0 + ko, &As[lb + chunk0]);
            gll16(gA1 + ko, &As[lb + chunk1]);
            gll16(gB0 + ko, &Bs[lb + chunk0]);
            gll16(gB1 + ko, &Bs[lb + chunk1]);
        }
        cur = (cur == 2) ? 0 : cur + 1;
    }
    #pragma unroll
    for (int mi = 0; mi < 4; ++mi) {
        int row = m0 + wm * 64 + mi * 16 + kq * 4;
        #pragma unroll
        for (int ni = 0; ni < 4; ++ni) {
            int col = n0 + wn * 64 + ni * 16 + rsub;
            float bcol = bias[col];
            #pragma unroll
            for (int r = 0; r < 4; ++r) {
                float x = acc[mi][ni][r] + bcol;
                float gg = 0.5f * x * (1.f + erff(x * 0.70710678118654752f));
                Hout[(size_t)(row + r) * H1 + col] = f2b(gg);
            }
        }
    }
}

// ---------------------------------------------------------------------------
// GEMM2: out slice = H @ w2 + b2 + time_emb.  (rows x 384) @ (384 x 256).
// Same 3-buffer pipeline. Rows span fused levels.
// ---------------------------------------------------------------------------
__global__ __launch_bounds__(256, 3) void gemm2_kernel(
    const unsigned short* __restrict__ A,   // rows x 384
    const unsigned short* __restrict__ Bt,  // 256 x 384 (= w2^T)
    const float* __restrict__ bias,
    const float* __restrict__ te,           // (8, 1110)
    float* __restrict__ out,                // (N, 8, 1110)
    int lv0)
{
    __shared__ __align__(16) unsigned short As[3 * 128 * 32];
    __shared__ __align__(16) unsigned short Bs[3 * 128 * 32];
    const int h = blockIdx.x, q = gridDim.x >> 3;
    const int l = (h & 7) * q + (h >> 3);
    const int m0 = (l >> 1) * 128, n0 = (l & 1) * 128;
    const int t = threadIdx.x, lane = t & 63, wv = t >> 6;
    const int wm = wv >> 1, wn = wv & 1;
    const int rsub = lane & 15, kq = lane >> 4;

    const int rA0 = t >> 2, sA0 = (t & 3) ^ ((rA0 >> 1) & 3);
    const int rA1 = (t + 256) >> 2, sA1 = ((t + 256) & 3) ^ ((rA1 >> 1) & 3);
    const unsigned short* gA0 = A  + (size_t)(m0 + rA0) * H1 + sA0 * 8;
    const unsigned short* gA1 = A  + (size_t)(m0 + rA1) * H1 + sA1 * 8;
    const unsigned short* gB0 = Bt + (size_t)(n0 + rA0) * H1 + sA0 * 8;
    const unsigned short* gB1 = Bt + (size_t)(n0 + rA1) * H1 + sA1 * 8;
    const int chunk0 = (t & ~63) * 8, chunk1 = (256 + (t & ~63)) * 8;

    f32x4 acc[4][4] = {};

    const int NSTEP = H1 / 32;  // 12
    #pragma unroll
    for (int p = 0; p < 3; ++p) {
        size_t ko = (size_t)p * 32;
        int lb = p * 4096;
        gll16(gA0 + ko, &As[lb + chunk0]); gll16(gA1 + ko, &As[lb + chunk1]);
        gll16(gB0 + ko, &Bs[lb + chunk0]); gll16(gB1 + ko, &Bs[lb + chunk1]);
    }
    int cur = 0;
    for (int st = 0; st < NSTEP; ++st) {
        const int rem = NSTEP - 1 - st;
        if (rem >= 2)      asm volatile("s_waitcnt vmcnt(8)" ::: "memory");
        else if (rem == 1) asm volatile("s_waitcnt vmcnt(4)" ::: "memory");
        else               asm volatile("s_waitcnt vmcnt(0)" ::: "memory");
        __builtin_amdgcn_s_barrier();
        __builtin_amdgcn_sched_barrier(0);
        const int lb = cur * 4096;
        bf16x8 af[4], bfr[4];
        #pragma unroll
        for (int mi = 0; mi < 4; ++mi) {
            int r = wm * 64 + mi * 16 + rsub;
            int phys = r * 4 + (kq ^ ((r >> 1) & 3));
            af[mi] = *(const bf16x8*)&As[lb + phys * 8];
        }
        #pragma unroll
        for (int ni = 0; ni < 4; ++ni) {
            int r = wn * 64 + ni * 16 + rsub;
            int phys = r * 4 + (kq ^ ((r >> 1) & 3));
            bfr[ni] = *(const bf16x8*)&Bs[lb + phys * 8];
        }
        #pragma unroll
        for (int mi = 0; mi < 4; ++mi)
            #pragma unroll
            for (int ni = 0; ni < 4; ++ni)
                acc[mi][ni] = __builtin_amdgcn_mfma_f32_16x16x32_bf16(
                    af[mi], bfr[ni], acc[mi][ni], 0, 0, 0);
        __builtin_amdgcn_sched_barrier(0);
        __builtin_amdgcn_s_barrier();
        __builtin_amdgcn_sched_barrier(0);
        if (st + 3 < NSTEP) {
            size_t ko = (size_t)(st + 3) * 32;
            gll16(gA0 + ko, &As[lb + chunk0]);
            gll16(gA1 + ko, &As[lb + chunk1]);
            gll16(gB0 + ko, &Bs[lb + chunk0]);
            gll16(gB1 + ko, &Bs[lb + chunk1]);
        }
        cur = (cur == 2) ? 0 : cur + 1;
    }
    #pragma unroll
    for (int mi = 0; mi < 4; ++mi) {
        int rowb = m0 + wm * 64 + mi * 16 + kq * 4;
        #pragma unroll
        for (int ni = 0; ni < 4; ++ni) {
            int col = n0 + wn * 64 + ni * 16 + rsub;
            float bcol = bias[col];
            #pragma unroll
            for (int r = 0; r < 4; ++r) {
                int row = rowb + r;
                int g = row >> 13, s = (row >> 10) & 7, n = row & 1023;
                int dcol = 2 + (lv0 + g) * H2 + col;
                out[((size_t)n * SN + s) * DOUT + dcol] =
                    acc[mi][ni][r] + bcol + te[s * DOUT + dcol];
            }
        }
    }
}

// ---------------------------------------------------------------------------
// Transpose + bf16-convert: in (K x Nw f32) -> out (Nw x Kp bf16), zero-pad.
// ---------------------------------------------------------------------------
__global__ __launch_bounds__(256) void conv_t_kernel(
    const float* __restrict__ in, unsigned short* __restrict__ outp,
    int K, int Nw, int Kp)
{
    __shared__ float tile[32][33];
    const int kb = blockIdx.x * 32, nb = blockIdx.y * 32;
    const int tx = threadIdx.x & 31, ty = threadIdx.x >> 5;
    #pragma unroll
    for (int i = 0; i < 32; i += 8) {
        int k = kb + ty + i, nn = nb + tx;
        tile[ty + i][tx] = (k < K && nn < Nw) ? in[(size_t)k * Nw + nn] : 0.f;
    }
    __syncthreads();
    #pragma unroll
    for (int i = 0; i < 32; i += 8) {
        int nn = nb + ty + i, k = kb + tx;
        if (nn < Nw) outp[(size_t)nn * Kp + k] = f2b(tile[tx][ty + i]);
    }
}

// Kernel D: vis, conf, rel_emb(84) + time_emb.
__global__ __launch_bounds__(128) void tail_kernel(
    const float* __restrict__ coords, const float* __restrict__ vis,
    const float* __restrict__ conf, const float* __restrict__ te,
    float* __restrict__ out)
{
    const int b = blockIdx.x;
    const int n = b >> 3, s = b & 7;
    const int d = threadIdx.x;
    if (d >= 86) return;
    const size_t ob = (size_t)b * DOUT;
    if (d == 0) {
        out[ob + 0] = vis[(size_t)s * NN + n] + te[s * DOUT + 0];
    } else if (d == 1) {
        out[ob + 1] = conf[(size_t)s * NN + n] + te[s * DOUT + 1];
    } else {
        int rd = d - 2;
        float cx = coords[((size_t)s * NN + n) * 2 + 0];
        float cy = coords[((size_t)s * NN + n) * 2 + 1];
        float rfx = 0.f, rfy = 0.f, rbx = 0.f, rby = 0.f;
        if (s < SN - 1) {
            rfx = cx - coords[((size_t)(s + 1) * NN + n) * 2 + 0];
            rfy = cy - coords[((size_t)(s + 1) * NN + n) * 2 + 1];
        }
        if (s > 0) {
            rbx = cx - coords[((size_t)(s - 1) * NN + n) * 2 + 0];
            rby = cy - coords[((size_t)(s - 1) * NN + n) * 2 + 1];
        }
        float r4[4] = {rfx / 128.f, rfy / 96.f, rbx / 128.f, rby / 96.f};
        float val;
        if (rd < 4) {
            val = r4[rd];
        } else if (rd < 44) {
            int q = rd - 4; int deg = q >> 2, comp = q & 3;
            val = sinf(r4[comp] * (float)(1 << deg));
        } else {
            int q = rd - 44; int deg = q >> 2, comp = q & 3;
            val = sinf(r4[comp] * (float)(1 << deg) + 1.57079632679489662f);
        }
        int od = 1026 + rd;
        out[ob + od] = val + te[s * DOUT + od];
    }
}

extern "C" void kernel_launch(void* const* d_in, const int* in_sizes, int n_in,
                              void* d_out, int out_size, void* d_ws, size_t ws_size,
                              hipStream_t stream) {
    const float* fmaps[4] = {(const float*)d_in[0], (const float*)d_in[2],
                             (const float*)d_in[4], (const float*)d_in[6]};
    const float* track[4] = {(const float*)d_in[1], (const float*)d_in[3],
                             (const float*)d_in[5], (const float*)d_in[7]};
    const float* coords = (const float*)d_in[8];
    const float* vis    = (const float*)d_in[9];
    const float* conf   = (const float*)d_in[10];
    const float* w1     = (const float*)d_in[11];
    const float* b1     = (const float*)d_in[12];
    const float* w2     = (const float*)d_in[13];
    const float* b2     = (const float*)d_in[14];
    const float* te     = (const float*)d_in[15];
    float* out = (float*)d_out;

    const int Hs[4] = {96, 48, 24, 12};
    const int Ws[4] = {128, 64, 32, 16};

    // ---- workspace layout ----
    char* wsb = (char*)d_ws;
    unsigned short* w1t = (unsigned short*)wsb;
    size_t off = (size_t)H1 * K1P * 2;
    unsigned short* w2t = (unsigned short*)(wsb + off);
    off += (size_t)H2 * H1 * 2;
    unsigned short* fpad[4];
    for (int l = 0; l < 4; ++l) {
        fpad[l] = (unsigned short*)(wsb + off);
        off += (size_t)SN * (Hs[l] + 8) * (Ws[l] + 8) * CC * 2;
    }
    off += 512;  // slack
    const size_t fixed = off;
    int n_lv = 4;
    while (n_lv > 1 &&
           fixed + (size_t)n_lv * SN * NN * (K1P + H1) * 2 > ws_size)
        n_lv >>= 1;
    unsigned short* volb = (unsigned short*)(wsb + fixed);
    unsigned short* hb   = volb + (size_t)n_lv * SN * NN * K1P;

    // ---- weight prep + fmap conversion ----
    conv_t_kernel<<<dim3(K1P / 32, H1 / 32), 256, 0, stream>>>(w1, w1t, 2401, H1, K1P);
    conv_t_kernel<<<dim3(H1 / 32, H2 / 32), 256, 0, stream>>>(w2, w2t, H1, H2, H1);
    for (int l = 0; l < 4; ++l)
        conv_fmap_kernel<<<SN * (Hs[l] + 8), 256, 0, stream>>>(
            fmaps[l], fpad[l], Hs[l], Ws[l]);

    for (int lv0 = 0; lv0 < 4; lv0 += n_lv) {
        sample_vol_kernel<<<n_lv * NN, 256, 0, stream>>>(
            fpad[0], fpad[1], fpad[2], fpad[3],
            track[0], track[1], track[2], track[3],
            coords, volb, lv0);
        const int rows = n_lv * SN * NN;
        gemm1_kernel<<<(rows / 128) * 3, 256, 0, stream>>>(volb, w1t, b1, hb);
        gemm2_kernel<<<(rows / 128) * 2, 256, 0, stream>>>(hb, w2t, b2, te, out, lv0);
    }
    tail_kernel<<<SN * NN, 128, 0, stream>>>(coords, vis, conf, te, out);
}